// Round 2
// baseline (1535.453 us; speedup 1.0000x reference)
//
#include <hip/hip_runtime.h>

#define D 128
#define GNUM 64
#define LNUM 4
#define BN_EPS 1e-5f

// ---------------- helpers ----------------
__device__ __forceinline__ float4 f4zero() { return make_float4(0.f, 0.f, 0.f, 0.f); }

__device__ __forceinline__ void mma_row(const float4 zr, const float4 w0,
                                        const float4 w1, const float4 w2,
                                        const float4 w3, float4& a) {
  a.x = fmaf(zr.x, w0.x, a.x); a.x = fmaf(zr.y, w1.x, a.x);
  a.x = fmaf(zr.z, w2.x, a.x); a.x = fmaf(zr.w, w3.x, a.x);
  a.y = fmaf(zr.x, w0.y, a.y); a.y = fmaf(zr.y, w1.y, a.y);
  a.y = fmaf(zr.z, w2.y, a.y); a.y = fmaf(zr.w, w3.y, a.y);
  a.z = fmaf(zr.x, w0.z, a.z); a.z = fmaf(zr.y, w1.z, a.z);
  a.z = fmaf(zr.z, w2.z, a.z); a.z = fmaf(zr.w, w3.z, a.z);
  a.w = fmaf(zr.x, w0.w, a.w); a.w = fmaf(zr.y, w1.w, a.w);
  a.w = fmaf(zr.z, w2.w, a.w); a.w = fmaf(zr.w, w3.w, a.w);
}

// ---------------- CSR build ----------------
__global__ void k_count(const int* __restrict__ ei, int E,
                        int* __restrict__ degi) {
  int e = blockIdx.x * 256 + threadIdx.x;
  if (e < E) {
    int dst = ei[(size_t)E + e];
    atomicAdd(&degi[dst], 1);
  }
}

__global__ void k_cnt(const int* __restrict__ batch, int N,
                      float* __restrict__ cnt) {
  int i = blockIdx.x * 256 + threadIdx.x;
  if (i < N) atomicAdd(&cnt[batch[i]], 1.0f);
}

__global__ __launch_bounds__(1024) void k_scan(const int* __restrict__ degi,
                                               int N, int* __restrict__ rowptr,
                                               int* __restrict__ cursor) {
  __shared__ int sums[1024];
  int tx = threadIdx.x;
  int chunk = (N + 1023) / 1024;
  int base = tx * chunk;
  int s = 0;
  for (int i = 0; i < chunk; ++i) {
    int idx = base + i;
    if (idx < N) s += degi[idx];
  }
  sums[tx] = s;
  __syncthreads();
  // Hillis-Steele inclusive scan
  for (int off = 1; off < 1024; off <<= 1) {
    int v = (tx >= off) ? sums[tx - off] : 0;
    __syncthreads();
    sums[tx] += v;
    __syncthreads();
  }
  int run = (tx == 0) ? 0 : sums[tx - 1];  // exclusive prefix of this chunk
  for (int i = 0; i < chunk; ++i) {
    int idx = base + i;
    if (idx < N) { rowptr[idx] = run; cursor[idx] = run; run += degi[idx]; }
  }
  if (tx == 0) rowptr[N] = sums[1023];
}

__global__ void k_fill(const int* __restrict__ ei, int E,
                       int* __restrict__ cursor, int* __restrict__ col) {
  int e = blockIdx.x * 256 + threadIdx.x;
  if (e < E) {
    int src = ei[e];
    int dst = ei[(size_t)E + e];
    int p = atomicAdd(&cursor[dst], 1);
    col[p] = src;
  }
}

// ---------------- per-layer kernels ----------------
// z[n] = h[n] + mean_{j in N(n)} h[j];  also zeroes BN stats accumulators.
__global__ __launch_bounds__(256) void k_aggz(const float* __restrict__ h,
                                              const int* __restrict__ rowptr,
                                              const int* __restrict__ col,
                                              int N, float* __restrict__ z,
                                              float* __restrict__ stats) {
  if (blockIdx.x == 0 && threadIdx.x < 2 * D) stats[threadIdx.x] = 0.f;
  int half = threadIdx.x >> 7;   // two nodes per block
  int d = threadIdx.x & (D - 1);
  int n = blockIdx.x * 2 + half;
  if (n >= N) return;
  int e0 = rowptr[n], e1 = rowptr[n + 1];
  float acc = 0.f;
  for (int j = e0; j < e1; ++j) acc += h[(size_t)col[j] * D + d];
  float degf = (float)(e1 - e0);
  float inv = degf > 0.f ? 1.f / degf : 0.f;  // deg clip(…,1): deg=0 -> agg=0
  z[(size_t)n * D + d] = h[(size_t)n * D + d] + acc * inv;
}

// t = z @ W + b  (64 rows per block); fused BN partial sums into stats[0..2D)
__global__ __launch_bounds__(256) void k_gemm1(const float* __restrict__ z,
                                               const float* __restrict__ W,
                                               const float* __restrict__ b,
                                               float* __restrict__ t,
                                               float* __restrict__ stats, int N) {
  __shared__ float zs[64 * D];       // 32 KB
  __shared__ float red[2 * 8 * D];   // 8 KB
  int tx = threadIdx.x;
  int r0 = blockIdx.x * 64;
  const float4* z4 = (const float4*)z;
  float4* zs4 = (float4*)zs;
#pragma unroll
  for (int j = 0; j < 8; ++j) {
    int idx = tx + 256 * j;
    int r = r0 + (idx >> 5);
    float4 v = f4zero();
    if (r < N) v = z4[(size_t)r0 * 32 + idx];
    zs4[idx] = v;
  }
  __syncthreads();
  int tc = tx & 31, tr = tx >> 5;
  const float4* W4 = (const float4*)W;
  float4 acc[8];
#pragma unroll
  for (int i = 0; i < 8; ++i) acc[i] = f4zero();
  for (int k4 = 0; k4 < 32; ++k4) {
    float4 w0 = W4[(k4 * 4 + 0) * 32 + tc];
    float4 w1 = W4[(k4 * 4 + 1) * 32 + tc];
    float4 w2 = W4[(k4 * 4 + 2) * 32 + tc];
    float4 w3 = W4[(k4 * 4 + 3) * 32 + tc];
#pragma unroll
    for (int i = 0; i < 8; ++i) {
      float4 zr = zs4[(tr * 8 + i) * 32 + k4];
      mma_row(zr, w0, w1, w2, w3, acc[i]);
    }
  }
  float4 bv = ((const float4*)b)[tc];
  float4 s4 = f4zero(), q4 = f4zero();
#pragma unroll
  for (int i = 0; i < 8; ++i) {
    int r = r0 + tr * 8 + i;
    if (r < N) {
      float4 v;
      v.x = acc[i].x + bv.x; v.y = acc[i].y + bv.y;
      v.z = acc[i].z + bv.z; v.w = acc[i].w + bv.w;
      ((float4*)t)[(size_t)r * 32 + tc] = v;
      s4.x += v.x; s4.y += v.y; s4.z += v.z; s4.w += v.w;
      q4.x += v.x * v.x; q4.y += v.y * v.y;
      q4.z += v.z * v.z; q4.w += v.w * v.w;
    }
  }
  ((float4*)red)[tr * 32 + tc] = s4;
  ((float4*)(red + 8 * D))[tr * 32 + tc] = q4;
  __syncthreads();
  if (tx < D) {
    float S = 0.f, Q = 0.f;
#pragma unroll
    for (int j = 0; j < 8; ++j) {
      S += red[j * D + tx];
      Q += red[8 * D + j * D + tx];
    }
    atomicAdd(&stats[tx], S);
    atomicAdd(&stats[D + tx], Q);
  }
}

// stats[2D..3D) = gamma*rstd ; stats[3D..4D) = beta - mu*gamma*rstd
__global__ void k_finalize(float* __restrict__ stats,
                           const float* __restrict__ gamma,
                           const float* __restrict__ beta, int N) {
  int c = threadIdx.x;
  float mu = stats[c] / (float)N;
  float var = stats[D + c] / (float)N - mu * mu;
  float rstd = rsqrtf(fmaxf(var, 0.f) + BN_EPS);
  float A = gamma[c] * rstd;
  stats[2 * D + c] = A;
  stats[3 * D + c] = beta[c] - mu * A;
}

// h = relu(bn(t)) @ W + b ; node_pool += h ; gsum[batch] += h
// NOTE: hout may alias t — each block reads its whole t-tile into LDS
// before writing the same rows, and tiles are block-disjoint.
__global__ __launch_bounds__(256) void k_gemm2(const float* __restrict__ t,
                                               const float* __restrict__ W,
                                               const float* __restrict__ b,
                                               const float* __restrict__ stats,
                                               const int* __restrict__ batch,
                                               float* __restrict__ hout,
                                               float* __restrict__ node_pool,
                                               float* __restrict__ gsum, int N) {
  __shared__ float zs[64 * D];  // 32 KB
  int tx = threadIdx.x;
  int r0 = blockIdx.x * 64;
  const float4* t4 = (const float4*)t;
  float4* zs4 = (float4*)zs;
  const float4* A4 = (const float4*)(stats + 2 * D);
  const float4* B4 = (const float4*)(stats + 3 * D);
#pragma unroll
  for (int j = 0; j < 8; ++j) {
    int idx = tx + 256 * j;
    int r = r0 + (idx >> 5);
    int c4 = idx & 31;
    float4 v = f4zero();
    if (r < N) {
      float4 u = t4[(size_t)r0 * 32 + idx];
      float4 a = A4[c4], bb = B4[c4];
      v.x = fmaxf(fmaf(u.x, a.x, bb.x), 0.f);
      v.y = fmaxf(fmaf(u.y, a.y, bb.y), 0.f);
      v.z = fmaxf(fmaf(u.z, a.z, bb.z), 0.f);
      v.w = fmaxf(fmaf(u.w, a.w, bb.w), 0.f);
    }
    zs4[idx] = v;
  }
  __syncthreads();
  int tc = tx & 31, tr = tx >> 5;
  const float4* W4 = (const float4*)W;
  float4 acc[8];
#pragma unroll
  for (int i = 0; i < 8; ++i) acc[i] = f4zero();
  for (int k4 = 0; k4 < 32; ++k4) {
    float4 w0 = W4[(k4 * 4 + 0) * 32 + tc];
    float4 w1 = W4[(k4 * 4 + 1) * 32 + tc];
    float4 w2 = W4[(k4 * 4 + 2) * 32 + tc];
    float4 w3 = W4[(k4 * 4 + 3) * 32 + tc];
#pragma unroll
    for (int i = 0; i < 8; ++i) {
      float4 zr = zs4[(tr * 8 + i) * 32 + k4];
      mma_row(zr, w0, w1, w2, w3, acc[i]);
    }
  }
  float4 bv = ((const float4*)b)[tc];
  int gprev = -1;
  float4 gacc = f4zero();
#pragma unroll
  for (int i = 0; i < 8; ++i) {
    int r = r0 + tr * 8 + i;
    if (r < N) {
      float4 v;
      v.x = acc[i].x + bv.x; v.y = acc[i].y + bv.y;
      v.z = acc[i].z + bv.z; v.w = acc[i].w + bv.w;
      ((float4*)hout)[(size_t)r * 32 + tc] = v;
      size_t np = (size_t)r * 32 + tc;
      float4 o = ((float4*)node_pool)[np];
      o.x += v.x; o.y += v.y; o.z += v.z; o.w += v.w;
      ((float4*)node_pool)[np] = o;
      int g = batch[r];
      if (g != gprev) {
        if (gprev >= 0) {
          atomicAdd(&gsum[gprev * D + tc * 4 + 0], gacc.x);
          atomicAdd(&gsum[gprev * D + tc * 4 + 1], gacc.y);
          atomicAdd(&gsum[gprev * D + tc * 4 + 2], gacc.z);
          atomicAdd(&gsum[gprev * D + tc * 4 + 3], gacc.w);
        }
        gacc = f4zero();
        gprev = g;
      }
      gacc.x += v.x; gacc.y += v.y; gacc.z += v.z; gacc.w += v.w;
    }
  }
  if (gprev >= 0) {
    atomicAdd(&gsum[gprev * D + tc * 4 + 0], gacc.x);
    atomicAdd(&gsum[gprev * D + tc * 4 + 1], gacc.y);
    atomicAdd(&gsum[gprev * D + tc * 4 + 2], gacc.z);
    atomicAdd(&gsum[gprev * D + tc * 4 + 3], gacc.w);
  }
}

__global__ void k_gpool(const float* __restrict__ gsum,
                        const float* __restrict__ cnt,
                        float* __restrict__ gpool) {
  int i = blockIdx.x * 256 + threadIdx.x;
  if (i < GNUM * D) {
    float c = cnt[i >> 7];
    gpool[i] = gsum[i] / fmaxf(c, 1.f);
  }
}

// ---------------- launch ----------------
extern "C" void kernel_launch(void* const* d_in, const int* in_sizes, int n_in,
                              void* d_out, int out_size, void* d_ws,
                              size_t ws_size, hipStream_t stream) {
  const float* x = (const float*)d_in[0];
  const int* ei = (const int*)d_in[1];     // int64 in reference -> int32 here
  const int* batch = (const int*)d_in[2];  // int64 in reference -> int32 here
  const float* W1 = (const float*)d_in[3];
  const float* b1 = (const float*)d_in[4];
  const float* gamma = (const float*)d_in[5];
  const float* beta = (const float*)d_in[6];
  const float* W2 = (const float*)d_in[7];
  const float* b2 = (const float*)d_in[8];
  int N = in_sizes[0] / D;
  int E = in_sizes[1] / 2;

  float* out = (float*)d_out;
  float* node_pool = out;
  float* g_pool = out + (size_t)N * D;

  char* wp = (char*)d_ws;
  float* h = (float*)wp;      wp += (size_t)N * D * 4;   // h / t (aliased)
  float* z = (float*)wp;      wp += (size_t)N * D * 4;
  float* gsum = (float*)wp;   wp += (size_t)GNUM * D * 4;
  float* cnt = (float*)wp;    wp += (size_t)GNUM * 4;
  float* stats = (float*)wp;  wp += (size_t)4 * D * 4;
  int* degi = (int*)wp;       wp += (size_t)N * 4;
  int* cursor = (int*)wp;     wp += (size_t)N * 4;
  int* rowptr = (int*)wp;     wp += (size_t)(N + 1) * 4;
  int* col = (int*)wp;        wp += (size_t)E * 4;
  float* t = h;  // alias: k_gemm2 reads t tile into LDS before writing hout tile

  hipMemsetAsync(node_pool, 0, (size_t)N * D * 4, stream);
  hipMemsetAsync(gsum, 0, (size_t)(GNUM * D + GNUM + 4 * D) * 4, stream);
  hipMemsetAsync(degi, 0, (size_t)N * 4, stream);

  int eb = (E + 255) / 256;
  int nb = (N + 255) / 256;
  k_count<<<eb, 256, 0, stream>>>(ei, E, degi);
  k_cnt<<<nb, 256, 0, stream>>>(batch, N, cnt);
  k_scan<<<1, 1024, 0, stream>>>(degi, N, rowptr, cursor);
  k_fill<<<eb, 256, 0, stream>>>(ei, E, cursor, col);

  int ab = (N + 1) / 2;        // aggz: 2 nodes per block
  int gb = (N + 63) / 64;      // gemm: 64 rows per block
  for (int l = 0; l < LNUM; ++l) {
    const float* hin = (l == 0) ? x : h;
    k_aggz<<<ab, 256, 0, stream>>>(hin, rowptr, col, N, z, stats);
    k_gemm1<<<gb, 256, 0, stream>>>(z, W1 + (size_t)l * D * D, b1 + (size_t)l * D,
                                    t, stats, N);
    k_finalize<<<1, D, 0, stream>>>(stats, gamma + (size_t)l * D,
                                    beta + (size_t)l * D, N);
    k_gemm2<<<gb, 256, 0, stream>>>(t, W2 + (size_t)l * D * D, b2 + (size_t)l * D,
                                    stats, batch, h, node_pool, gsum, N);
  }
  k_gpool<<<(GNUM * D + 255) / 256, 256, 0, stream>>>(gsum, cnt, g_pool);
}

// Round 3
// 874.963 us; speedup vs baseline: 1.7549x; 1.7549x over previous
//
#include <hip/hip_runtime.h>

#define D 128
#define GNUM 64
#define LNUM 4
#define BN_EPS 1e-5f

typedef short bf16x8 __attribute__((ext_vector_type(8)));       // 8 bf16 = 4 VGPR
typedef float f32x4 __attribute__((ext_vector_type(4)));
typedef unsigned short u16x8 __attribute__((ext_vector_type(8)));
typedef unsigned short u16x4 __attribute__((ext_vector_type(4)));

__device__ __forceinline__ float bf2f(unsigned short u) {
  union { unsigned int i; float f; } v; v.i = ((unsigned int)u) << 16; return v.f;
}
__device__ __forceinline__ unsigned short f2bf(float f) {
  union { float f; unsigned int i; } v; v.f = f;
  unsigned int b = v.i;
  return (unsigned short)((b + 0x7FFFu + ((b >> 16) & 1u)) >> 16);
}

// ---------------- CSR build ----------------
__global__ void k_count(const int* __restrict__ ei, int E, int* __restrict__ degi) {
  int e = blockIdx.x * 256 + threadIdx.x;
  if (e < E) atomicAdd(&degi[ei[(size_t)E + e]], 1);
}

__global__ __launch_bounds__(1024) void k_scan(const int* __restrict__ degi,
                                               int N, int* __restrict__ rowptr,
                                               int* __restrict__ cursor) {
  __shared__ int sums[1024];
  int tx = threadIdx.x;
  int chunk = (N + 1023) / 1024;
  int base = tx * chunk;
  int s = 0;
  for (int i = 0; i < chunk; ++i) { int idx = base + i; if (idx < N) s += degi[idx]; }
  sums[tx] = s;
  __syncthreads();
  for (int off = 1; off < 1024; off <<= 1) {
    int v = (tx >= off) ? sums[tx - off] : 0;
    __syncthreads();
    sums[tx] += v;
    __syncthreads();
  }
  int run = (tx == 0) ? 0 : sums[tx - 1];
  for (int i = 0; i < chunk; ++i) {
    int idx = base + i;
    if (idx < N) { rowptr[idx] = run; cursor[idx] = run; run += degi[idx]; }
  }
  if (tx == 0) rowptr[N] = sums[1023];
}

__global__ void k_fill(const int* __restrict__ ei, int E,
                       int* __restrict__ cursor, int* __restrict__ col) {
  int e = blockIdx.x * 256 + threadIdx.x;
  if (e < E) {
    int p = atomicAdd(&cursor[ei[(size_t)E + e]], 1);
    col[p] = ei[e];
  }
}

// graph boundaries via binary search on sorted batch (replaces atomic k_cnt)
__global__ void k_bounds(const int* __restrict__ batch, int N, int* __restrict__ bound) {
  int g = threadIdx.x;
  if (g > GNUM) return;
  int lo = 0, hi = N;
  while (lo < hi) { int mid = (lo + hi) >> 1; if (batch[mid] < g) lo = mid + 1; else hi = mid; }
  bound[g] = lo;
}

// ---------------- prep: fp32 -> bf16 ----------------
__global__ void k_prep_x(const float* __restrict__ x, unsigned short* __restrict__ hx, int total4) {
  int i = blockIdx.x * 256 + threadIdx.x;
  if (i < total4) {
    f32x4 v = ((const f32x4*)x)[i];
    u16x4 o; o[0] = f2bf(v[0]); o[1] = f2bf(v[1]); o[2] = f2bf(v[2]); o[3] = f2bf(v[3]);
    ((u16x4*)hx)[i] = o;
  }
}

// transpose W[k][n] -> wt[n][k], bf16.  blockIdx.x = matrix index (0..7)
__global__ __launch_bounds__(256) void k_prep_w(const float* __restrict__ W1,
                                                const float* __restrict__ W2,
                                                unsigned short* __restrict__ wt) {
  int l = blockIdx.x;
  const float* W = (l < LNUM) ? (W1 + (size_t)l * D * D) : (W2 + (size_t)(l - LNUM) * D * D);
  unsigned short* o = wt + (size_t)l * D * D;
#pragma unroll
  for (int i = 0; i < 64; ++i) {
    int idx = threadIdx.x + 256 * i;       // idx = k*128 + n
    int k = idx >> 7, n = idx & 127;
    o[n * D + k] = f2bf(W[idx]);
  }
}

// ---------------- aggregation: z = h + mean_nbr(h), bf16 ----------------
__global__ __launch_bounds__(256) void k_aggz(const unsigned short* __restrict__ hin,
                                              const int* __restrict__ rowptr,
                                              const int* __restrict__ col,
                                              int N, unsigned short* __restrict__ z) {
  int l = threadIdx.x & 63;          // one wave per node; lane covers 2 cols
  int w = threadIdx.x >> 6;
  int n = blockIdx.x * 4 + w;
  if (n >= N) return;
  int e0 = rowptr[n], e1 = rowptr[n + 1];
  const unsigned int* h32 = (const unsigned int*)hin;
  float a0 = 0.f, a1 = 0.f;
  for (int j = e0; j < e1; ++j) {
    unsigned int v = h32[(size_t)col[j] * 64 + l];
    a0 += bf2f((unsigned short)(v & 0xFFFFu));
    a1 += bf2f((unsigned short)(v >> 16));
  }
  float inv = (e1 > e0) ? 1.f / (float)(e1 - e0) : 0.f;
  unsigned int hv = h32[(size_t)n * 64 + l];
  float z0 = bf2f((unsigned short)(hv & 0xFFFFu)) + a0 * inv;
  float z1 = bf2f((unsigned short)(hv >> 16)) + a1 * inv;
  ((unsigned int*)z)[(size_t)n * 64 + l] = ((unsigned int)f2bf(z1) << 16) | (unsigned int)f2bf(z0);
}

// ---------------- GEMM1: t = z @ W1 + b1 (bf16 MFMA), + BN partials ----------------
__global__ __launch_bounds__(256) void k_gemm1(const unsigned short* __restrict__ z,
                                               const unsigned short* __restrict__ wt,
                                               const float* __restrict__ bias,
                                               unsigned short* __restrict__ t,
                                               float* __restrict__ partials, int N) {
  __shared__ union { unsigned short zt[64 * D]; float red[2 * 8 * D]; } uA;  // 16KB/8KB
  __shared__ union { unsigned short wl[D * D]; float out[64 * D]; } uB;      // 32KB
  int tx = threadIdx.x;
  int r0 = blockIdx.x * 64;
  // stage A tile (swizzled) + W tile (swizzled)
  const u16x8* zg = (const u16x8*)(z + (size_t)r0 * D);
#pragma unroll
  for (int i = 0; i < 4; ++i) {
    int cid = tx + 256 * i;
    int row = cid >> 4, c16 = cid & 15;
    u16x8 v = zg[cid];
    *(u16x8*)((char*)uA.zt + row * 256 + ((c16 * 16) ^ ((row & 7) << 4))) = v;
  }
  const u16x8* wg = (const u16x8*)wt;
#pragma unroll
  for (int i = 0; i < 8; ++i) {
    int cid = tx + 256 * i;
    int row = cid >> 4, c16 = cid & 15;
    u16x8 v = wg[cid];
    *(u16x8*)((char*)uB.wl + row * 256 + ((c16 * 16) ^ ((row & 7) << 4))) = v;
  }
  __syncthreads();
  int l = tx & 63, w = tx >> 6;
  int lm = l & 15, lg = l >> 4;
  f32x4 acc[8];
#pragma unroll
  for (int c = 0; c < 8; ++c) { float bv = bias[c * 16 + lm]; acc[c] = (f32x4){bv, bv, bv, bv}; }
  int arow = 16 * w + lm;
  const char* zb = (const char*)uA.zt + arow * 256;
  int aswz = (arow & 7) << 4;
#pragma unroll
  for (int kt = 0; kt < 4; ++kt) {
    int koff = kt * 64 + lg * 16;
    bf16x8 af = *(const bf16x8*)(zb + (koff ^ aswz));
#pragma unroll
    for (int c = 0; c < 8; ++c) {
      int n = c * 16 + lm;
      bf16x8 bfr = *(const bf16x8*)((const char*)uB.wl + n * 256 + (koff ^ ((n & 7) << 4)));
      acc[c] = __builtin_amdgcn_mfma_f32_16x16x32_bf16(af, bfr, acc[c], 0, 0, 0);
    }
  }
  __syncthreads();  // wl free -> out
#pragma unroll
  for (int c = 0; c < 8; ++c)
#pragma unroll
    for (int r = 0; r < 4; ++r)
      uB.out[(16 * w + 4 * lg + r) * D + c * 16 + lm] = acc[c][r];
  __syncthreads();
  // linear pass: t store (bf16) + per-block BN partials
  int tc = tx & 31, tr = tx >> 5;
  f32x4 s = {0.f, 0.f, 0.f, 0.f}, q = {0.f, 0.f, 0.f, 0.f};
#pragma unroll
  for (int i = 0; i < 8; ++i) {
    int row = i * 8 + tr;
    f32x4 v = *(f32x4*)&uB.out[row * D + tc * 4];
    u16x4 o; o[0] = f2bf(v[0]); o[1] = f2bf(v[1]); o[2] = f2bf(v[2]); o[3] = f2bf(v[3]);
    *(u16x4*)(t + (size_t)(r0 + row) * D + tc * 4) = o;   // t is padded
    if (r0 + row < N) { s += v; q += v * v; }
  }
  *(f32x4*)&uA.red[tr * D + tc * 4] = s;
  *(f32x4*)&uA.red[8 * D + tr * D + tc * 4] = q;
  __syncthreads();
  int colx = tx & 127, which = tx >> 7;
  float S = 0.f;
#pragma unroll
  for (int j = 0; j < 8; ++j) S += uA.red[which * 8 * D + j * D + colx];
  partials[(size_t)blockIdx.x * 256 + tx] = S;
}

// reduce partials -> stats[0..127]=gamma*rstd, stats[128..255]=beta-mu*gamma*rstd
__global__ __launch_bounds__(256) void k_finalize(const float* __restrict__ partials, int NB,
                                                  const float* __restrict__ gamma,
                                                  const float* __restrict__ beta,
                                                  float* __restrict__ stats, int N) {
  __shared__ float sh[256];
  int tx = threadIdx.x;
  float S = 0.f;
#pragma unroll 8
  for (int b = 0; b < NB; ++b) S += partials[(size_t)b * 256 + tx];
  sh[tx] = S;
  __syncthreads();
  if (tx < D) {
    float mu = sh[tx] / (float)N;
    float var = sh[D + tx] / (float)N - mu * mu;
    float rstd = rsqrtf(fmaxf(var, 0.f) + BN_EPS);
    float A = gamma[tx] * rstd;
    stats[tx] = A;
    stats[D + tx] = beta[tx] - mu * A;
  }
}

// ---------------- GEMM2: h = relu(bn(t)) @ W2 + b2 ; node_pool += h ----------------
__global__ __launch_bounds__(256) void k_gemm2(const unsigned short* __restrict__ t,
                                               const unsigned short* __restrict__ wt,
                                               const float* __restrict__ bias,
                                               const float* __restrict__ stats,
                                               unsigned short* __restrict__ h,
                                               float* __restrict__ node_pool, int N) {
  __shared__ unsigned short at[64 * D];                                      // 16KB
  __shared__ union { unsigned short wl[D * D]; float out[64 * D]; } uB;      // 32KB
  int tx = threadIdx.x;
  int r0 = blockIdx.x * 64;
  const u16x8* tg = (const u16x8*)(t + (size_t)r0 * D);
#pragma unroll
  for (int i = 0; i < 4; ++i) {
    int cid = tx + 256 * i;
    int row = cid >> 4, c16 = cid & 15;
    u16x8 v = tg[cid];
    int c0 = c16 * 8;
    f32x4 a0 = *(const f32x4*)&stats[c0];
    f32x4 a1 = *(const f32x4*)&stats[c0 + 4];
    f32x4 b0 = *(const f32x4*)&stats[D + c0];
    f32x4 b1v = *(const f32x4*)&stats[D + c0 + 4];
    u16x8 o;
    o[0] = f2bf(fmaxf(bf2f(v[0]) * a0[0] + b0[0], 0.f));
    o[1] = f2bf(fmaxf(bf2f(v[1]) * a0[1] + b0[1], 0.f));
    o[2] = f2bf(fmaxf(bf2f(v[2]) * a0[2] + b0[2], 0.f));
    o[3] = f2bf(fmaxf(bf2f(v[3]) * a0[3] + b0[3], 0.f));
    o[4] = f2bf(fmaxf(bf2f(v[4]) * a1[0] + b1v[0], 0.f));
    o[5] = f2bf(fmaxf(bf2f(v[5]) * a1[1] + b1v[1], 0.f));
    o[6] = f2bf(fmaxf(bf2f(v[6]) * a1[2] + b1v[2], 0.f));
    o[7] = f2bf(fmaxf(bf2f(v[7]) * a1[3] + b1v[3], 0.f));
    *(u16x8*)((char*)at + row * 256 + ((c16 * 16) ^ ((row & 7) << 4))) = o;
  }
  const u16x8* wg = (const u16x8*)wt;
#pragma unroll
  for (int i = 0; i < 8; ++i) {
    int cid = tx + 256 * i;
    int row = cid >> 4, c16 = cid & 15;
    u16x8 v = wg[cid];
    *(u16x8*)((char*)uB.wl + row * 256 + ((c16 * 16) ^ ((row & 7) << 4))) = v;
  }
  __syncthreads();
  int l = tx & 63, w = tx >> 6;
  int lm = l & 15, lg = l >> 4;
  f32x4 acc[8];
#pragma unroll
  for (int c = 0; c < 8; ++c) { float bv = bias[c * 16 + lm]; acc[c] = (f32x4){bv, bv, bv, bv}; }
  int arow = 16 * w + lm;
  const char* ab = (const char*)at + arow * 256;
  int aswz = (arow & 7) << 4;
#pragma unroll
  for (int kt = 0; kt < 4; ++kt) {
    int koff = kt * 64 + lg * 16;
    bf16x8 af = *(const bf16x8*)(ab + (koff ^ aswz));
#pragma unroll
    for (int c = 0; c < 8; ++c) {
      int n = c * 16 + lm;
      bf16x8 bfr = *(const bf16x8*)((const char*)uB.wl + n * 256 + (koff ^ ((n & 7) << 4)));
      acc[c] = __builtin_amdgcn_mfma_f32_16x16x32_bf16(af, bfr, acc[c], 0, 0, 0);
    }
  }
  __syncthreads();
#pragma unroll
  for (int c = 0; c < 8; ++c)
#pragma unroll
    for (int r = 0; r < 4; ++r)
      uB.out[(16 * w + 4 * lg + r) * D + c * 16 + lm] = acc[c][r];
  __syncthreads();
  int tc = tx & 31, tr = tx >> 5;
#pragma unroll
  for (int i = 0; i < 8; ++i) {
    int row = i * 8 + tr;
    int gr = r0 + row;
    if (gr < N) {
      f32x4 v = *(f32x4*)&uB.out[row * D + tc * 4];
      f32x4* np = (f32x4*)(node_pool + (size_t)gr * D + tc * 4);
      f32x4 o = *np;
      o += v;
      *np = o;
      u16x4 hb; hb[0] = f2bf(v[0]); hb[1] = f2bf(v[1]); hb[2] = f2bf(v[2]); hb[3] = f2bf(v[3]);
      *(u16x4*)(h + (size_t)gr * D + tc * 4) = hb;
    }
  }
}

// ---------------- pooling: g_pool[g] = mean over rows of node_pool ----------------
__global__ __launch_bounds__(256) void k_gpool(const float* __restrict__ np,
                                               const int* __restrict__ bound,
                                               float* __restrict__ gp) {
  __shared__ float red[8 * D];
  int g = blockIdx.x;
  int s = bound[g], e = bound[g + 1];
  int tc = threadIdx.x & 31, tr = threadIdx.x >> 5;
  f32x4 a = {0.f, 0.f, 0.f, 0.f};
  for (int r = s + tr; r < e; r += 8)
    a += *(const f32x4*)(np + (size_t)r * D + tc * 4);
  *(f32x4*)&red[tr * D + tc * 4] = a;
  __syncthreads();
  if (threadIdx.x < D) {
    float v = 0.f;
#pragma unroll
    for (int j = 0; j < 8; ++j) v += red[j * D + threadIdx.x];
    float c = (float)(e - s);
    gp[(size_t)g * D + threadIdx.x] = v / fmaxf(c, 1.f);
  }
}

// ---------------- launch ----------------
extern "C" void kernel_launch(void* const* d_in, const int* in_sizes, int n_in,
                              void* d_out, int out_size, void* d_ws,
                              size_t ws_size, hipStream_t stream) {
  const float* x = (const float*)d_in[0];
  const int* ei = (const int*)d_in[1];
  const int* batch = (const int*)d_in[2];
  const float* W1 = (const float*)d_in[3];
  const float* b1 = (const float*)d_in[4];
  const float* gamma = (const float*)d_in[5];
  const float* beta = (const float*)d_in[6];
  const float* W2 = (const float*)d_in[7];
  const float* b2 = (const float*)d_in[8];
  int N = in_sizes[0] / D;
  int E = in_sizes[1] / 2;
  int Npad = (N + 63) & ~63;
  int gb = Npad / 64;

  float* out = (float*)d_out;
  float* node_pool = out;
  float* g_pool = out + (size_t)N * D;

  char* wp = (char*)d_ws;
  unsigned short* t_hx = (unsigned short*)wp; wp += (size_t)Npad * D * 2;  // t, aliased x-bf16
  unsigned short* h = (unsigned short*)wp;    wp += (size_t)Npad * D * 2;
  unsigned short* z = (unsigned short*)wp;    wp += (size_t)Npad * D * 2;
  unsigned short* wt = (unsigned short*)wp;   wp += (size_t)8 * D * D * 2;
  float* partials = (float*)wp;               wp += (size_t)gb * 256 * 4;
  float* stats = (float*)wp;                  wp += (size_t)2 * D * 4;
  int* bound = (int*)wp;                      wp += (size_t)(GNUM + 4) * 4;
  int* degi = (int*)wp;                       wp += (size_t)N * 4;
  int* rowptr = (int*)wp;                     wp += (size_t)(N + 1) * 4;
  int* col = (int*)wp;                        wp += (size_t)E * 4;
  int* cursor = (int*)partials;  // overlay: cursor dead before partials written

  hipMemsetAsync(node_pool, 0, (size_t)N * D * 4, stream);
  hipMemsetAsync(degi, 0, (size_t)N * 4, stream);

  int eb = (E + 255) / 256;
  k_prep_w<<<8, 256, 0, stream>>>(W1, W2, wt);
  k_prep_x<<<(N * 32 + 255) / 256, 256, 0, stream>>>(x, t_hx, N * 32);
  k_count<<<eb, 256, 0, stream>>>(ei, E, degi);
  k_scan<<<1, 1024, 0, stream>>>(degi, N, rowptr, cursor);
  k_fill<<<eb, 256, 0, stream>>>(ei, E, cursor, col);
  k_bounds<<<1, 128, 0, stream>>>(batch, N, bound);

  int ab = (N + 3) / 4;
  for (int ll = 0; ll < LNUM; ++ll) {
    const unsigned short* hin = (ll == 0) ? t_hx : h;
    k_aggz<<<ab, 256, 0, stream>>>(hin, rowptr, col, N, z);
    k_gemm1<<<gb, 256, 0, stream>>>(z, wt + (size_t)ll * D * D, b1 + (size_t)ll * D,
                                    t_hx, partials, N);
    k_finalize<<<1, 256, 0, stream>>>(partials, gb, gamma + (size_t)ll * D,
                                      beta + (size_t)ll * D, stats, N);
    k_gemm2<<<gb, 256, 0, stream>>>(t_hx, wt + (size_t)(LNUM + ll) * D * D,
                                    b2 + (size_t)ll * D, stats, h, node_pool, N);
  }
  k_gpool<<<GNUM, 256, 0, stream>>>(node_pool, bound, g_pool);
}

// Round 4
// 665.512 us; speedup vs baseline: 2.3072x; 1.3147x over previous
//
#include <hip/hip_runtime.h>

#define D 128
#define GNUM 64
#define LNUM 4
#define BN_EPS 1e-5f

typedef short bf16x8 __attribute__((ext_vector_type(8)));       // 8 bf16 = 4 VGPR
typedef float f32x4 __attribute__((ext_vector_type(4)));
typedef unsigned short u16x8 __attribute__((ext_vector_type(8)));
typedef unsigned short u16x4 __attribute__((ext_vector_type(4)));

__device__ __forceinline__ float bf2f(unsigned short u) {
  union { unsigned int i; float f; } v; v.i = ((unsigned int)u) << 16; return v.f;
}
__device__ __forceinline__ unsigned short f2bf(float f) {
  union { float f; unsigned int i; } v; v.f = f;
  unsigned int b = v.i;
  return (unsigned short)((b + 0x7FFFu + ((b >> 16) & 1u)) >> 16);
}

// ---------------- CSR build ----------------
__global__ void k_count(const int* __restrict__ ei, int E, int* __restrict__ degi) {
  int e = blockIdx.x * 256 + threadIdx.x;
  if (e < E) atomicAdd(&degi[ei[(size_t)E + e]], 1);
}

// hierarchical scan, stage 1: per-block sum of 256 degrees
__global__ __launch_bounds__(256) void k_bsum(const int* __restrict__ degi, int N,
                                              int* __restrict__ bsum) {
  __shared__ int sh[256];
  int tx = threadIdx.x;
  int i = blockIdx.x * 256 + tx;
  sh[tx] = (i < N) ? degi[i] : 0;
  __syncthreads();
#pragma unroll
  for (int off = 128; off > 0; off >>= 1) {
    if (tx < off) sh[tx] += sh[tx + off];
    __syncthreads();
  }
  if (tx == 0) bsum[blockIdx.x] = sh[0];
}

// stage 2: single-block exclusive scan of <=256 block sums
__global__ __launch_bounds__(256) void k_bscan(const int* __restrict__ bsum, int NB,
                                               int* __restrict__ boff,
                                               int* __restrict__ rowptr, int N, int E) {
  __shared__ int sh[256];
  int tx = threadIdx.x;
  int v = (tx < NB) ? bsum[tx] : 0;
  sh[tx] = v;
  __syncthreads();
#pragma unroll
  for (int off = 1; off < 256; off <<= 1) {
    int u = (tx >= off) ? sh[tx - off] : 0;
    __syncthreads();
    sh[tx] += u;
    __syncthreads();
  }
  boff[tx] = sh[tx] - v;  // exclusive prefix
  if (tx == 0) rowptr[N] = E;
}

// stage 3: per-block intra-scan + global offset -> rowptr & cursor
__global__ __launch_bounds__(256) void k_rowptr(const int* __restrict__ degi, int N,
                                                const int* __restrict__ boff,
                                                int* __restrict__ rowptr,
                                                int* __restrict__ cursor) {
  __shared__ int sh[256];
  int tx = threadIdx.x;
  int i = blockIdx.x * 256 + tx;
  int d = (i < N) ? degi[i] : 0;
  sh[tx] = d;
  __syncthreads();
#pragma unroll
  for (int off = 1; off < 256; off <<= 1) {
    int u = (tx >= off) ? sh[tx - off] : 0;
    __syncthreads();
    sh[tx] += u;
    __syncthreads();
  }
  if (i < N) {
    int excl = sh[tx] - d + boff[blockIdx.x];
    rowptr[i] = excl;
    cursor[i] = excl;
  }
}

__global__ void k_fill(const int* __restrict__ ei, int E,
                       int* __restrict__ cursor, int* __restrict__ col) {
  int e = blockIdx.x * 256 + threadIdx.x;
  if (e < E) {
    int p = atomicAdd(&cursor[ei[(size_t)E + e]], 1);
    col[p] = ei[e];
  }
}

// graph boundaries via binary search on sorted batch
__global__ void k_bounds(const int* __restrict__ batch, int N, int* __restrict__ bound) {
  int g = threadIdx.x;
  if (g > GNUM) return;
  int lo = 0, hi = N;
  while (lo < hi) { int mid = (lo + hi) >> 1; if (batch[mid] < g) lo = mid + 1; else hi = mid; }
  bound[g] = lo;
}

// ---------------- prep: fp32 -> bf16 ----------------
__global__ void k_prep_x(const float* __restrict__ x, unsigned short* __restrict__ hx, int total4) {
  int i = blockIdx.x * 256 + threadIdx.x;
  if (i < total4) {
    f32x4 v = ((const f32x4*)x)[i];
    u16x4 o; o[0] = f2bf(v[0]); o[1] = f2bf(v[1]); o[2] = f2bf(v[2]); o[3] = f2bf(v[3]);
    ((u16x4*)hx)[i] = o;
  }
}

// transpose W[k][n] -> wt[n][k], bf16.  blockIdx.x = matrix index (0..7)
__global__ __launch_bounds__(256) void k_prep_w(const float* __restrict__ W1,
                                                const float* __restrict__ W2,
                                                unsigned short* __restrict__ wt) {
  int l = blockIdx.x;
  const float* W = (l < LNUM) ? (W1 + (size_t)l * D * D) : (W2 + (size_t)(l - LNUM) * D * D);
  unsigned short* o = wt + (size_t)l * D * D;
#pragma unroll
  for (int i = 0; i < 64; ++i) {
    int idx = threadIdx.x + 256 * i;       // idx = k*128 + n
    int k = idx >> 7, n = idx & 127;
    o[n * D + k] = f2bf(W[idx]);
  }
}

// ---------------- aggregation: z = h + mean_nbr(h), bf16 ----------------
__global__ __launch_bounds__(256) void k_aggz(const unsigned short* __restrict__ hin,
                                              const int* __restrict__ rowptr,
                                              const int* __restrict__ col,
                                              int N, unsigned short* __restrict__ z) {
  int l = threadIdx.x & 63;          // one wave per node; lane covers 2 cols
  int w = threadIdx.x >> 6;
  int n = blockIdx.x * 4 + w;
  if (n >= N) return;
  int e0 = rowptr[n], e1 = rowptr[n + 1];
  const unsigned int* h32 = (const unsigned int*)hin;
  float a0 = 0.f, a1 = 0.f;
  for (int j = e0; j < e1; ++j) {
    unsigned int v = h32[(size_t)col[j] * 64 + l];
    a0 += bf2f((unsigned short)(v & 0xFFFFu));
    a1 += bf2f((unsigned short)(v >> 16));
  }
  float inv = (e1 > e0) ? 1.f / (float)(e1 - e0) : 0.f;
  unsigned int hv = h32[(size_t)n * 64 + l];
  float z0 = bf2f((unsigned short)(hv & 0xFFFFu)) + a0 * inv;
  float z1 = bf2f((unsigned short)(hv >> 16)) + a1 * inv;
  ((unsigned int*)z)[(size_t)n * 64 + l] = ((unsigned int)f2bf(z1) << 16) | (unsigned int)f2bf(z0);
}

// ---------------- GEMM1: t = z @ W1 + b1 (bf16 MFMA), + BN partials ----------------
__global__ __launch_bounds__(256) void k_gemm1(const unsigned short* __restrict__ z,
                                               const unsigned short* __restrict__ wt,
                                               const float* __restrict__ bias,
                                               unsigned short* __restrict__ t,
                                               float* __restrict__ partials, int N) {
  __shared__ union { unsigned short zt[64 * D]; float red[2 * 8 * D]; } uA;  // 16KB/8KB
  __shared__ union { unsigned short wl[D * D]; float out[64 * D]; } uB;      // 32KB
  int tx = threadIdx.x;
  int r0 = blockIdx.x * 64;
  const u16x8* zg = (const u16x8*)(z + (size_t)r0 * D);
#pragma unroll
  for (int i = 0; i < 4; ++i) {
    int cid = tx + 256 * i;
    int row = cid >> 4, c16 = cid & 15;
    u16x8 v = zg[cid];
    *(u16x8*)((char*)uA.zt + row * 256 + ((c16 * 16) ^ ((row & 7) << 4))) = v;
  }
  const u16x8* wg = (const u16x8*)wt;
#pragma unroll
  for (int i = 0; i < 8; ++i) {
    int cid = tx + 256 * i;
    int row = cid >> 4, c16 = cid & 15;
    u16x8 v = wg[cid];
    *(u16x8*)((char*)uB.wl + row * 256 + ((c16 * 16) ^ ((row & 7) << 4))) = v;
  }
  __syncthreads();
  int l = tx & 63, w = tx >> 6;
  int lm = l & 15, lg = l >> 4;
  f32x4 acc[8];
#pragma unroll
  for (int c = 0; c < 8; ++c) { float bv = bias[c * 16 + lm]; acc[c] = (f32x4){bv, bv, bv, bv}; }
  int arow = 16 * w + lm;
  const char* zb = (const char*)uA.zt + arow * 256;
  int aswz = (arow & 7) << 4;
#pragma unroll
  for (int kt = 0; kt < 4; ++kt) {
    int koff = kt * 64 + lg * 16;
    bf16x8 af = *(const bf16x8*)(zb + (koff ^ aswz));
#pragma unroll
    for (int c = 0; c < 8; ++c) {
      int n = c * 16 + lm;
      bf16x8 bfr = *(const bf16x8*)((const char*)uB.wl + n * 256 + (koff ^ ((n & 7) << 4)));
      acc[c] = __builtin_amdgcn_mfma_f32_16x16x32_bf16(af, bfr, acc[c], 0, 0, 0);
    }
  }
  __syncthreads();  // wl free -> out
#pragma unroll
  for (int c = 0; c < 8; ++c)
#pragma unroll
    for (int r = 0; r < 4; ++r)
      uB.out[(16 * w + 4 * lg + r) * D + c * 16 + lm] = acc[c][r];
  __syncthreads();
  int tc = tx & 31, tr = tx >> 5;
  f32x4 s = {0.f, 0.f, 0.f, 0.f}, q = {0.f, 0.f, 0.f, 0.f};
#pragma unroll
  for (int i = 0; i < 8; ++i) {
    int row = i * 8 + tr;
    f32x4 v = *(f32x4*)&uB.out[row * D + tc * 4];
    u16x4 o; o[0] = f2bf(v[0]); o[1] = f2bf(v[1]); o[2] = f2bf(v[2]); o[3] = f2bf(v[3]);
    *(u16x4*)(t + (size_t)(r0 + row) * D + tc * 4) = o;   // t is padded
    if (r0 + row < N) { s += v; q += v * v; }
  }
  *(f32x4*)&uA.red[tr * D + tc * 4] = s;
  *(f32x4*)&uA.red[8 * D + tr * D + tc * 4] = q;
  __syncthreads();
  int colx = tx & 127, which = tx >> 7;
  float S = 0.f;
#pragma unroll
  for (int j = 0; j < 8; ++j) S += uA.red[which * 8 * D + j * D + colx];
  partials[(size_t)blockIdx.x * 256 + tx] = S;
}

// reduce stage 1: 64 blocks stride over gemm1 blocks -> partial2[64][256]
__global__ __launch_bounds__(256) void k_red1(const float* __restrict__ partials, int NB,
                                              float* __restrict__ partial2) {
  int tx = threadIdx.x;
  float S = 0.f;
  for (int b = blockIdx.x; b < NB; b += 64) S += partials[(size_t)b * 256 + tx];
  partial2[(size_t)blockIdx.x * 256 + tx] = S;
}

// reduce stage 2 -> stats[0..127]=gamma*rstd, stats[128..255]=beta-mu*gamma*rstd
__global__ __launch_bounds__(256) void k_finalize(const float* __restrict__ partial2,
                                                  const float* __restrict__ gamma,
                                                  const float* __restrict__ beta,
                                                  float* __restrict__ stats, int N) {
  __shared__ float sh[256];
  int tx = threadIdx.x;
  float S = 0.f;
#pragma unroll 8
  for (int b = 0; b < 64; ++b) S += partial2[(size_t)b * 256 + tx];
  sh[tx] = S;
  __syncthreads();
  if (tx < D) {
    float mu = sh[tx] / (float)N;
    float var = sh[D + tx] / (float)N - mu * mu;
    float rstd = rsqrtf(fmaxf(var, 0.f) + BN_EPS);
    float A = gamma[tx] * rstd;
    stats[tx] = A;
    stats[D + tx] = beta[tx] - mu * A;
  }
}

// ---------------- GEMM2: h = relu(bn(t)) @ W2 + b2 ; node_pool += h ----------------
__global__ __launch_bounds__(256) void k_gemm2(const unsigned short* __restrict__ t,
                                               const unsigned short* __restrict__ wt,
                                               const float* __restrict__ bias,
                                               const float* __restrict__ stats,
                                               unsigned short* __restrict__ h,
                                               float* __restrict__ node_pool, int N) {
  __shared__ unsigned short at[64 * D];                                      // 16KB
  __shared__ union { unsigned short wl[D * D]; float out[64 * D]; } uB;      // 32KB
  int tx = threadIdx.x;
  int r0 = blockIdx.x * 64;
  const u16x8* tg = (const u16x8*)(t + (size_t)r0 * D);
#pragma unroll
  for (int i = 0; i < 4; ++i) {
    int cid = tx + 256 * i;
    int row = cid >> 4, c16 = cid & 15;
    u16x8 v = tg[cid];
    int c0 = c16 * 8;
    f32x4 a0 = *(const f32x4*)&stats[c0];
    f32x4 a1 = *(const f32x4*)&stats[c0 + 4];
    f32x4 b0 = *(const f32x4*)&stats[D + c0];
    f32x4 b1v = *(const f32x4*)&stats[D + c0 + 4];
    u16x8 o;
    o[0] = f2bf(fmaxf(bf2f(v[0]) * a0[0] + b0[0], 0.f));
    o[1] = f2bf(fmaxf(bf2f(v[1]) * a0[1] + b0[1], 0.f));
    o[2] = f2bf(fmaxf(bf2f(v[2]) * a0[2] + b0[2], 0.f));
    o[3] = f2bf(fmaxf(bf2f(v[3]) * a0[3] + b0[3], 0.f));
    o[4] = f2bf(fmaxf(bf2f(v[4]) * a1[0] + b1v[0], 0.f));
    o[5] = f2bf(fmaxf(bf2f(v[5]) * a1[1] + b1v[1], 0.f));
    o[6] = f2bf(fmaxf(bf2f(v[6]) * a1[2] + b1v[2], 0.f));
    o[7] = f2bf(fmaxf(bf2f(v[7]) * a1[3] + b1v[3], 0.f));
    *(u16x8*)((char*)at + row * 256 + ((c16 * 16) ^ ((row & 7) << 4))) = o;
  }
  const u16x8* wg = (const u16x8*)wt;
#pragma unroll
  for (int i = 0; i < 8; ++i) {
    int cid = tx + 256 * i;
    int row = cid >> 4, c16 = cid & 15;
    u16x8 v = wg[cid];
    *(u16x8*)((char*)uB.wl + row * 256 + ((c16 * 16) ^ ((row & 7) << 4))) = v;
  }
  __syncthreads();
  int l = tx & 63, w = tx >> 6;
  int lm = l & 15, lg = l >> 4;
  f32x4 acc[8];
#pragma unroll
  for (int c = 0; c < 8; ++c) { float bv = bias[c * 16 + lm]; acc[c] = (f32x4){bv, bv, bv, bv}; }
  int arow = 16 * w + lm;
  const char* ab = (const char*)at + arow * 256;
  int aswz = (arow & 7) << 4;
#pragma unroll
  for (int kt = 0; kt < 4; ++kt) {
    int koff = kt * 64 + lg * 16;
    bf16x8 af = *(const bf16x8*)(ab + (koff ^ aswz));
#pragma unroll
    for (int c = 0; c < 8; ++c) {
      int n = c * 16 + lm;
      bf16x8 bfr = *(const bf16x8*)((const char*)uB.wl + n * 256 + (koff ^ ((n & 7) << 4)));
      acc[c] = __builtin_amdgcn_mfma_f32_16x16x32_bf16(af, bfr, acc[c], 0, 0, 0);
    }
  }
  __syncthreads();
#pragma unroll
  for (int c = 0; c < 8; ++c)
#pragma unroll
    for (int r = 0; r < 4; ++r)
      uB.out[(16 * w + 4 * lg + r) * D + c * 16 + lm] = acc[c][r];
  __syncthreads();
  int tc = tx & 31, tr = tx >> 5;
#pragma unroll
  for (int i = 0; i < 8; ++i) {
    int row = i * 8 + tr;
    int gr = r0 + row;
    if (gr < N) {
      f32x4 v = *(f32x4*)&uB.out[row * D + tc * 4];
      f32x4* np = (f32x4*)(node_pool + (size_t)gr * D + tc * 4);
      f32x4 o = *np;
      o += v;
      *np = o;
      u16x4 hb; hb[0] = f2bf(v[0]); hb[1] = f2bf(v[1]); hb[2] = f2bf(v[2]); hb[3] = f2bf(v[3]);
      *(u16x4*)(h + (size_t)gr * D + tc * 4) = hb;
    }
  }
}

// ---------------- pooling: g_pool[g] = mean over rows of node_pool ----------------
__global__ __launch_bounds__(256) void k_gpool(const float* __restrict__ np,
                                               const int* __restrict__ bound,
                                               float* __restrict__ gp) {
  __shared__ float red[8 * D];
  int g = blockIdx.x;
  int s = bound[g], e = bound[g + 1];
  int tc = threadIdx.x & 31, tr = threadIdx.x >> 5;
  f32x4 a = {0.f, 0.f, 0.f, 0.f};
  for (int r = s + tr; r < e; r += 8)
    a += *(const f32x4*)(np + (size_t)r * D + tc * 4);
  *(f32x4*)&red[tr * D + tc * 4] = a;
  __syncthreads();
  if (threadIdx.x < D) {
    float v = 0.f;
#pragma unroll
    for (int j = 0; j < 8; ++j) v += red[j * D + threadIdx.x];
    float c = (float)(e - s);
    gp[(size_t)g * D + threadIdx.x] = v / fmaxf(c, 1.f);
  }
}

// ---------------- launch ----------------
extern "C" void kernel_launch(void* const* d_in, const int* in_sizes, int n_in,
                              void* d_out, int out_size, void* d_ws,
                              size_t ws_size, hipStream_t stream) {
  const float* x = (const float*)d_in[0];
  const int* ei = (const int*)d_in[1];
  const int* batch = (const int*)d_in[2];
  const float* W1 = (const float*)d_in[3];
  const float* b1 = (const float*)d_in[4];
  const float* gamma = (const float*)d_in[5];
  const float* beta = (const float*)d_in[6];
  const float* W2 = (const float*)d_in[7];
  const float* b2 = (const float*)d_in[8];
  int N = in_sizes[0] / D;
  int E = in_sizes[1] / 2;
  int Npad = (N + 63) & ~63;
  int gb = Npad / 64;
  int NB = (N + 255) / 256;   // scan blocks (<=256 for N<=65536)

  float* out = (float*)d_out;
  float* node_pool = out;
  float* g_pool = out + (size_t)N * D;

  char* wp = (char*)d_ws;
  unsigned short* t_hx = (unsigned short*)wp; wp += (size_t)Npad * D * 2;  // t, aliased x-bf16
  unsigned short* h = (unsigned short*)wp;    wp += (size_t)Npad * D * 2;
  unsigned short* z = (unsigned short*)wp;    wp += (size_t)Npad * D * 2;
  unsigned short* wt = (unsigned short*)wp;   wp += (size_t)8 * D * D * 2;
  float* partials = (float*)wp;               wp += (size_t)gb * 256 * 4;
  float* partial2 = (float*)wp;               wp += (size_t)64 * 256 * 4;
  float* stats = (float*)wp;                  wp += (size_t)2 * D * 4;
  int* bound = (int*)wp;                      wp += (size_t)(GNUM + 4) * 4;
  int* degi = (int*)wp;                       wp += (size_t)N * 4;
  int* rowptr = (int*)wp;                     wp += (size_t)(N + 1) * 4;
  int* bsum = (int*)wp;                       wp += (size_t)256 * 4;
  int* boff = (int*)wp;                       wp += (size_t)256 * 4;
  int* col = (int*)wp;                        wp += (size_t)E * 4;
  int* cursor = (int*)partials;  // overlay: cursor dead before partials written

  hipMemsetAsync(node_pool, 0, (size_t)N * D * 4, stream);
  hipMemsetAsync(degi, 0, (size_t)N * 4, stream);

  int eb = (E + 255) / 256;
  k_prep_w<<<8, 256, 0, stream>>>(W1, W2, wt);
  k_prep_x<<<(N * 32 + 255) / 256, 256, 0, stream>>>(x, t_hx, N * 32);
  k_count<<<eb, 256, 0, stream>>>(ei, E, degi);
  k_bsum<<<NB, 256, 0, stream>>>(degi, N, bsum);
  k_bscan<<<1, 256, 0, stream>>>(bsum, NB, boff, rowptr, N, E);
  k_rowptr<<<NB, 256, 0, stream>>>(degi, N, boff, rowptr, cursor);
  k_fill<<<eb, 256, 0, stream>>>(ei, E, cursor, col);
  k_bounds<<<1, 128, 0, stream>>>(batch, N, bound);

  int ab = (N + 3) / 4;
  for (int ll = 0; ll < LNUM; ++ll) {
    const unsigned short* hin = (ll == 0) ? t_hx : h;
    k_aggz<<<ab, 256, 0, stream>>>(hin, rowptr, col, N, z);
    k_gemm1<<<gb, 256, 0, stream>>>(z, wt + (size_t)ll * D * D, b1 + (size_t)ll * D,
                                    t_hx, partials, N);
    k_red1<<<64, 256, 0, stream>>>(partials, gb, partial2);
    k_finalize<<<1, 256, 0, stream>>>(partial2, gamma + (size_t)ll * D,
                                      beta + (size_t)ll * D, stats, N);
    k_gemm2<<<gb, 256, 0, stream>>>(t_hx, wt + (size_t)(LNUM + ll) * D * D,
                                    b2 + (size_t)ll * D, stats, h, node_pool, N);
  }
  k_gpool<<<GNUM, 256, 0, stream>>>(node_pool, bound, g_pool);
}

// Round 5
// 477.119 us; speedup vs baseline: 3.2182x; 1.3949x over previous
//
#include <hip/hip_runtime.h>

#define D 128
#define GNUM 64
#define LNUM 4
#define BN_EPS 1e-5f

typedef short bf16x8 __attribute__((ext_vector_type(8)));       // 8 bf16 = 4 VGPR
typedef float f32x4 __attribute__((ext_vector_type(4)));
typedef unsigned short u16x8 __attribute__((ext_vector_type(8)));
typedef unsigned short u16x4 __attribute__((ext_vector_type(4)));

__device__ __forceinline__ float bf2f(unsigned short u) {
  union { unsigned int i; float f; } v; v.i = ((unsigned int)u) << 16; return v.f;
}
__device__ __forceinline__ unsigned short f2bf(float f) {
  union { float f; unsigned int i; } v; v.f = f;
  unsigned int b = v.i;
  return (unsigned short)((b + 0x7FFFu + ((b >> 16) & 1u)) >> 16);
}

// ---------------- CSR build ----------------
__global__ void k_count(const int* __restrict__ ei, int E, int* __restrict__ degi) {
  int e = blockIdx.x * 256 + threadIdx.x;
  if (e < E) atomicAdd(&degi[ei[(size_t)E + e]], 1);
}

// hierarchical scan, stage 1: per-block sum of 256 degrees
__global__ __launch_bounds__(256) void k_bsum(const int* __restrict__ degi, int N,
                                              int* __restrict__ bsum) {
  __shared__ int sh[256];
  int tx = threadIdx.x;
  int i = blockIdx.x * 256 + tx;
  sh[tx] = (i < N) ? degi[i] : 0;
  __syncthreads();
#pragma unroll
  for (int off = 128; off > 0; off >>= 1) {
    if (tx < off) sh[tx] += sh[tx + off];
    __syncthreads();
  }
  if (tx == 0) bsum[blockIdx.x] = sh[0];
}

// stage 2: single-block exclusive scan of <=256 block sums
__global__ __launch_bounds__(256) void k_bscan(const int* __restrict__ bsum, int NB,
                                               int* __restrict__ boff,
                                               int* __restrict__ rowptr, int N, int E) {
  __shared__ int sh[256];
  int tx = threadIdx.x;
  int v = (tx < NB) ? bsum[tx] : 0;
  sh[tx] = v;
  __syncthreads();
#pragma unroll
  for (int off = 1; off < 256; off <<= 1) {
    int u = (tx >= off) ? sh[tx - off] : 0;
    __syncthreads();
    sh[tx] += u;
    __syncthreads();
  }
  boff[tx] = sh[tx] - v;  // exclusive prefix
  if (tx == 0) rowptr[N] = E;
}

// stage 3: per-block intra-scan + global offset -> rowptr & cursor
__global__ __launch_bounds__(256) void k_rowptr(const int* __restrict__ degi, int N,
                                                const int* __restrict__ boff,
                                                int* __restrict__ rowptr,
                                                int* __restrict__ cursor) {
  __shared__ int sh[256];
  int tx = threadIdx.x;
  int i = blockIdx.x * 256 + tx;
  int d = (i < N) ? degi[i] : 0;
  sh[tx] = d;
  __syncthreads();
#pragma unroll
  for (int off = 1; off < 256; off <<= 1) {
    int u = (tx >= off) ? sh[tx - off] : 0;
    __syncthreads();
    sh[tx] += u;
    __syncthreads();
  }
  if (i < N) {
    int excl = sh[tx] - d + boff[blockIdx.x];
    rowptr[i] = excl;
    cursor[i] = excl;
  }
}

__global__ void k_fill(const int* __restrict__ ei, int E,
                       int* __restrict__ cursor, int* __restrict__ col) {
  int e = blockIdx.x * 256 + threadIdx.x;
  if (e < E) {
    int p = atomicAdd(&cursor[ei[(size_t)E + e]], 1);
    col[p] = ei[e];
  }
}

// graph boundaries via binary search on sorted batch
__global__ void k_bounds(const int* __restrict__ batch, int N, int* __restrict__ bound) {
  int g = threadIdx.x;
  if (g > GNUM) return;
  int lo = 0, hi = N;
  while (lo < hi) { int mid = (lo + hi) >> 1; if (batch[mid] < g) lo = mid + 1; else hi = mid; }
  bound[g] = lo;
}

// ---------------- prep: fp32 -> bf16 ----------------
__global__ void k_prep_x(const float* __restrict__ x, unsigned short* __restrict__ hx, int total4) {
  int i = blockIdx.x * 256 + threadIdx.x;
  if (i < total4) {
    f32x4 v = ((const f32x4*)x)[i];
    u16x4 o; o[0] = f2bf(v[0]); o[1] = f2bf(v[1]); o[2] = f2bf(v[2]); o[3] = f2bf(v[3]);
    ((u16x4*)hx)[i] = o;
  }
}

// transpose W[k][n] -> wt[n][k], bf16.  blockIdx.x = matrix index (0..7)
__global__ __launch_bounds__(256) void k_prep_w(const float* __restrict__ W1,
                                                const float* __restrict__ W2,
                                                unsigned short* __restrict__ wt) {
  int l = blockIdx.x;
  const float* W = (l < LNUM) ? (W1 + (size_t)l * D * D) : (W2 + (size_t)(l - LNUM) * D * D);
  unsigned short* o = wt + (size_t)l * D * D;
#pragma unroll
  for (int i = 0; i < 64; ++i) {
    int idx = threadIdx.x + 256 * i;       // idx = k*128 + n
    int k = idx >> 7, n = idx & 127;
    o[n * D + k] = f2bf(W[idx]);
  }
}

// ---------------- aggregation: z = h + mean_nbr(h), bf16 ----------------
// One wave per node. Lanes split into 4 groups of 16; each group processes a
// different edge, each lane loads 16B of the 256B row -> 4 edges in flight per
// vmem instruction; unroll x2 -> up to 8. Butterfly-reduce groups at the end.
__global__ __launch_bounds__(256) void k_aggz(const unsigned short* __restrict__ hin,
                                              const int* __restrict__ rowptr,
                                              const int* __restrict__ col,
                                              int N, unsigned short* __restrict__ z) {
  int tx = threadIdx.x;
  int w = tx >> 6, l = tx & 63;
  int g = l >> 4;             // edge subgroup 0..3
  int c = l & 15;             // 16B slice of the row
  int n = blockIdx.x * 4 + w;
  if (n >= N) return;
  int e0 = rowptr[n], e1 = rowptr[n + 1];
  const u16x8* h8 = (const u16x8*)hin;   // one row = 16 x u16x8
  f32x4 a0 = {0.f, 0.f, 0.f, 0.f}, a1 = {0.f, 0.f, 0.f, 0.f};
  f32x4 b0 = {0.f, 0.f, 0.f, 0.f}, b1 = {0.f, 0.f, 0.f, 0.f};
  int j = e0 + g;
  for (; j + 4 < e1; j += 8) {
    int cj0 = col[j];
    int cj1 = col[j + 4];
    u16x8 v0 = h8[(size_t)cj0 * 16 + c];
    u16x8 v1 = h8[(size_t)cj1 * 16 + c];
    a0[0] += bf2f(v0[0]); a0[1] += bf2f(v0[1]); a0[2] += bf2f(v0[2]); a0[3] += bf2f(v0[3]);
    a1[0] += bf2f(v0[4]); a1[1] += bf2f(v0[5]); a1[2] += bf2f(v0[6]); a1[3] += bf2f(v0[7]);
    b0[0] += bf2f(v1[0]); b0[1] += bf2f(v1[1]); b0[2] += bf2f(v1[2]); b0[3] += bf2f(v1[3]);
    b1[0] += bf2f(v1[4]); b1[1] += bf2f(v1[5]); b1[2] += bf2f(v1[6]); b1[3] += bf2f(v1[7]);
  }
  if (j < e1) {
    int cj = col[j];
    u16x8 v = h8[(size_t)cj * 16 + c];
    a0[0] += bf2f(v[0]); a0[1] += bf2f(v[1]); a0[2] += bf2f(v[2]); a0[3] += bf2f(v[3]);
    a1[0] += bf2f(v[4]); a1[1] += bf2f(v[5]); a1[2] += bf2f(v[6]); a1[3] += bf2f(v[7]);
  }
  a0 += b0; a1 += b1;
  // butterfly reduce across the 4 groups (lane masks 16, 32)
#pragma unroll
  for (int m = 16; m <= 32; m <<= 1) {
#pragma unroll
    for (int i = 0; i < 4; ++i) {
      a0[i] += __shfl_xor(a0[i], m, 64);
      a1[i] += __shfl_xor(a1[i], m, 64);
    }
  }
  if (g == 0) {
    float inv = (e1 > e0) ? 1.f / (float)(e1 - e0) : 0.f;
    u16x8 hv = h8[(size_t)n * 16 + c];
    u16x8 o;
    o[0] = f2bf(bf2f(hv[0]) + a0[0] * inv);
    o[1] = f2bf(bf2f(hv[1]) + a0[1] * inv);
    o[2] = f2bf(bf2f(hv[2]) + a0[2] * inv);
    o[3] = f2bf(bf2f(hv[3]) + a0[3] * inv);
    o[4] = f2bf(bf2f(hv[4]) + a1[0] * inv);
    o[5] = f2bf(bf2f(hv[5]) + a1[1] * inv);
    o[6] = f2bf(bf2f(hv[6]) + a1[2] * inv);
    o[7] = f2bf(bf2f(hv[7]) + a1[3] * inv);
    ((u16x8*)z)[(size_t)n * 16 + c] = o;
  }
}

// ---------------- GEMM1: t = z @ W1 + b1 (bf16 MFMA), + BN partials ----------------
__global__ __launch_bounds__(256) void k_gemm1(const unsigned short* __restrict__ z,
                                               const unsigned short* __restrict__ wt,
                                               const float* __restrict__ bias,
                                               unsigned short* __restrict__ t,
                                               float* __restrict__ partials, int N) {
  __shared__ union { unsigned short zt[64 * D]; float red[2 * 8 * D]; } uA;  // 16KB/8KB
  __shared__ union { unsigned short wl[D * D]; float out[64 * D]; } uB;      // 32KB
  int tx = threadIdx.x;
  int r0 = blockIdx.x * 64;
  const u16x8* zg = (const u16x8*)(z + (size_t)r0 * D);
#pragma unroll
  for (int i = 0; i < 4; ++i) {
    int cid = tx + 256 * i;
    int row = cid >> 4, c16 = cid & 15;
    u16x8 v = zg[cid];
    *(u16x8*)((char*)uA.zt + row * 256 + ((c16 * 16) ^ ((row & 7) << 4))) = v;
  }
  const u16x8* wg = (const u16x8*)wt;
#pragma unroll
  for (int i = 0; i < 8; ++i) {
    int cid = tx + 256 * i;
    int row = cid >> 4, c16 = cid & 15;
    u16x8 v = wg[cid];
    *(u16x8*)((char*)uB.wl + row * 256 + ((c16 * 16) ^ ((row & 7) << 4))) = v;
  }
  __syncthreads();
  int l = tx & 63, w = tx >> 6;
  int lm = l & 15, lg = l >> 4;
  f32x4 acc[8];
#pragma unroll
  for (int c = 0; c < 8; ++c) { float bv = bias[c * 16 + lm]; acc[c] = (f32x4){bv, bv, bv, bv}; }
  int arow = 16 * w + lm;
  const char* zb = (const char*)uA.zt + arow * 256;
  int aswz = (arow & 7) << 4;
#pragma unroll
  for (int kt = 0; kt < 4; ++kt) {
    int koff = kt * 64 + lg * 16;
    bf16x8 af = *(const bf16x8*)(zb + (koff ^ aswz));
#pragma unroll
    for (int c = 0; c < 8; ++c) {
      int n = c * 16 + lm;
      bf16x8 bfr = *(const bf16x8*)((const char*)uB.wl + n * 256 + (koff ^ ((n & 7) << 4)));
      acc[c] = __builtin_amdgcn_mfma_f32_16x16x32_bf16(af, bfr, acc[c], 0, 0, 0);
    }
  }
  __syncthreads();  // wl free -> out
#pragma unroll
  for (int c = 0; c < 8; ++c)
#pragma unroll
    for (int r = 0; r < 4; ++r)
      uB.out[(16 * w + 4 * lg + r) * D + c * 16 + lm] = acc[c][r];
  __syncthreads();
  int tc = tx & 31, tr = tx >> 5;
  f32x4 s = {0.f, 0.f, 0.f, 0.f}, q = {0.f, 0.f, 0.f, 0.f};
#pragma unroll
  for (int i = 0; i < 8; ++i) {
    int row = i * 8 + tr;
    f32x4 v = *(f32x4*)&uB.out[row * D + tc * 4];
    u16x4 o; o[0] = f2bf(v[0]); o[1] = f2bf(v[1]); o[2] = f2bf(v[2]); o[3] = f2bf(v[3]);
    *(u16x4*)(t + (size_t)(r0 + row) * D + tc * 4) = o;   // t is padded
    if (r0 + row < N) { s += v; q += v * v; }
  }
  *(f32x4*)&uA.red[tr * D + tc * 4] = s;
  *(f32x4*)&uA.red[8 * D + tr * D + tc * 4] = q;
  __syncthreads();
  int colx = tx & 127, which = tx >> 7;
  float S = 0.f;
#pragma unroll
  for (int j = 0; j < 8; ++j) S += uA.red[which * 8 * D + j * D + colx];
  partials[(size_t)blockIdx.x * 256 + tx] = S;
}

// reduce stage 1: 64 blocks stride over gemm1 blocks -> partial2[64][256]
__global__ __launch_bounds__(256) void k_red1(const float* __restrict__ partials, int NB,
                                              float* __restrict__ partial2) {
  int tx = threadIdx.x;
  float S = 0.f;
  for (int b = blockIdx.x; b < NB; b += 64) S += partials[(size_t)b * 256 + tx];
  partial2[(size_t)blockIdx.x * 256 + tx] = S;
}

// reduce stage 2 -> stats[0..127]=gamma*rstd, stats[128..255]=beta-mu*gamma*rstd
__global__ __launch_bounds__(256) void k_finalize(const float* __restrict__ partial2,
                                                  const float* __restrict__ gamma,
                                                  const float* __restrict__ beta,
                                                  float* __restrict__ stats, int N) {
  __shared__ float sh[256];
  int tx = threadIdx.x;
  float S = 0.f;
#pragma unroll 8
  for (int b = 0; b < 64; ++b) S += partial2[(size_t)b * 256 + tx];
  sh[tx] = S;
  __syncthreads();
  if (tx < D) {
    float mu = sh[tx] / (float)N;
    float var = sh[D + tx] / (float)N - mu * mu;
    float rstd = rsqrtf(fmaxf(var, 0.f) + BN_EPS);
    float A = gamma[tx] * rstd;
    stats[tx] = A;
    stats[D + tx] = beta[tx] - mu * A;
  }
}

// ---------------- GEMM2: h = relu(bn(t)) @ W2 + b2 ; node_pool += h ----------------
__global__ __launch_bounds__(256) void k_gemm2(const unsigned short* __restrict__ t,
                                               const unsigned short* __restrict__ wt,
                                               const float* __restrict__ bias,
                                               const float* __restrict__ stats,
                                               unsigned short* __restrict__ h,
                                               float* __restrict__ node_pool, int N) {
  __shared__ unsigned short at[64 * D];                                      // 16KB
  __shared__ union { unsigned short wl[D * D]; float out[64 * D]; } uB;      // 32KB
  int tx = threadIdx.x;
  int r0 = blockIdx.x * 64;
  const u16x8* tg = (const u16x8*)(t + (size_t)r0 * D);
#pragma unroll
  for (int i = 0; i < 4; ++i) {
    int cid = tx + 256 * i;
    int row = cid >> 4, c16 = cid & 15;
    u16x8 v = tg[cid];
    int c0 = c16 * 8;
    f32x4 a0 = *(const f32x4*)&stats[c0];
    f32x4 a1 = *(const f32x4*)&stats[c0 + 4];
    f32x4 b0 = *(const f32x4*)&stats[D + c0];
    f32x4 b1v = *(const f32x4*)&stats[D + c0 + 4];
    u16x8 o;
    o[0] = f2bf(fmaxf(bf2f(v[0]) * a0[0] + b0[0], 0.f));
    o[1] = f2bf(fmaxf(bf2f(v[1]) * a0[1] + b0[1], 0.f));
    o[2] = f2bf(fmaxf(bf2f(v[2]) * a0[2] + b0[2], 0.f));
    o[3] = f2bf(fmaxf(bf2f(v[3]) * a0[3] + b0[3], 0.f));
    o[4] = f2bf(fmaxf(bf2f(v[4]) * a1[0] + b1v[0], 0.f));
    o[5] = f2bf(fmaxf(bf2f(v[5]) * a1[1] + b1v[1], 0.f));
    o[6] = f2bf(fmaxf(bf2f(v[6]) * a1[2] + b1v[2], 0.f));
    o[7] = f2bf(fmaxf(bf2f(v[7]) * a1[3] + b1v[3], 0.f));
    *(u16x8*)((char*)at + row * 256 + ((c16 * 16) ^ ((row & 7) << 4))) = o;
  }
  const u16x8* wg = (const u16x8*)wt;
#pragma unroll
  for (int i = 0; i < 8; ++i) {
    int cid = tx + 256 * i;
    int row = cid >> 4, c16 = cid & 15;
    u16x8 v = wg[cid];
    *(u16x8*)((char*)uB.wl + row * 256 + ((c16 * 16) ^ ((row & 7) << 4))) = v;
  }
  __syncthreads();
  int l = tx & 63, w = tx >> 6;
  int lm = l & 15, lg = l >> 4;
  f32x4 acc[8];
#pragma unroll
  for (int c = 0; c < 8; ++c) { float bv = bias[c * 16 + lm]; acc[c] = (f32x4){bv, bv, bv, bv}; }
  int arow = 16 * w + lm;
  const char* ab = (const char*)at + arow * 256;
  int aswz = (arow & 7) << 4;
#pragma unroll
  for (int kt = 0; kt < 4; ++kt) {
    int koff = kt * 64 + lg * 16;
    bf16x8 af = *(const bf16x8*)(ab + (koff ^ aswz));
#pragma unroll
    for (int c = 0; c < 8; ++c) {
      int n = c * 16 + lm;
      bf16x8 bfr = *(const bf16x8*)((const char*)uB.wl + n * 256 + (koff ^ ((n & 7) << 4)));
      acc[c] = __builtin_amdgcn_mfma_f32_16x16x32_bf16(af, bfr, acc[c], 0, 0, 0);
    }
  }
  __syncthreads();
#pragma unroll
  for (int c = 0; c < 8; ++c)
#pragma unroll
    for (int r = 0; r < 4; ++r)
      uB.out[(16 * w + 4 * lg + r) * D + c * 16 + lm] = acc[c][r];
  __syncthreads();
  int tc = tx & 31, tr = tx >> 5;
#pragma unroll
  for (int i = 0; i < 8; ++i) {
    int row = i * 8 + tr;
    int gr = r0 + row;
    if (gr < N) {
      f32x4 v = *(f32x4*)&uB.out[row * D + tc * 4];
      f32x4* np = (f32x4*)(node_pool + (size_t)gr * D + tc * 4);
      f32x4 o = *np;
      o += v;
      *np = o;
      u16x4 hb; hb[0] = f2bf(v[0]); hb[1] = f2bf(v[1]); hb[2] = f2bf(v[2]); hb[3] = f2bf(v[3]);
      *(u16x4*)(h + (size_t)gr * D + tc * 4) = hb;
    }
  }
}

// ---------------- pooling: g_pool[g] = mean over rows of node_pool ----------------
__global__ __launch_bounds__(256) void k_gpool(const float* __restrict__ np,
                                               const int* __restrict__ bound,
                                               float* __restrict__ gp) {
  __shared__ float red[8 * D];
  int g = blockIdx.x;
  int s = bound[g], e = bound[g + 1];
  int tc = threadIdx.x & 31, tr = threadIdx.x >> 5;
  f32x4 a = {0.f, 0.f, 0.f, 0.f};
  for (int r = s + tr; r < e; r += 8)
    a += *(const f32x4*)(np + (size_t)r * D + tc * 4);
  *(f32x4*)&red[tr * D + tc * 4] = a;
  __syncthreads();
  if (threadIdx.x < D) {
    float v = 0.f;
#pragma unroll
    for (int j = 0; j < 8; ++j) v += red[j * D + threadIdx.x];
    float c = (float)(e - s);
    gp[(size_t)g * D + threadIdx.x] = v / fmaxf(c, 1.f);
  }
}

// ---------------- launch ----------------
extern "C" void kernel_launch(void* const* d_in, const int* in_sizes, int n_in,
                              void* d_out, int out_size, void* d_ws,
                              size_t ws_size, hipStream_t stream) {
  const float* x = (const float*)d_in[0];
  const int* ei = (const int*)d_in[1];
  const int* batch = (const int*)d_in[2];
  const float* W1 = (const float*)d_in[3];
  const float* b1 = (const float*)d_in[4];
  const float* gamma = (const float*)d_in[5];
  const float* beta = (const float*)d_in[6];
  const float* W2 = (const float*)d_in[7];
  const float* b2 = (const float*)d_in[8];
  int N = in_sizes[0] / D;
  int E = in_sizes[1] / 2;
  int Npad = (N + 63) & ~63;
  int gb = Npad / 64;
  int NB = (N + 255) / 256;   // scan blocks (<=256 for N<=65536)

  float* out = (float*)d_out;
  float* node_pool = out;
  float* g_pool = out + (size_t)N * D;

  char* wp = (char*)d_ws;
  unsigned short* t_hx = (unsigned short*)wp; wp += (size_t)Npad * D * 2;  // t, aliased x-bf16
  unsigned short* h = (unsigned short*)wp;    wp += (size_t)Npad * D * 2;
  unsigned short* z = (unsigned short*)wp;    wp += (size_t)Npad * D * 2;
  unsigned short* wt = (unsigned short*)wp;   wp += (size_t)8 * D * D * 2;
  float* partials = (float*)wp;               wp += (size_t)gb * 256 * 4;
  float* partial2 = (float*)wp;               wp += (size_t)64 * 256 * 4;
  float* stats = (float*)wp;                  wp += (size_t)2 * D * 4;
  int* bound = (int*)wp;                      wp += (size_t)(GNUM + 4) * 4;
  int* degi = (int*)wp;                       wp += (size_t)N * 4;
  int* rowptr = (int*)wp;                     wp += (size_t)(N + 1) * 4;
  int* bsum = (int*)wp;                       wp += (size_t)256 * 4;
  int* boff = (int*)wp;                       wp += (size_t)256 * 4;
  int* col = (int*)wp;                        wp += (size_t)E * 4;
  int* cursor = (int*)partials;  // overlay: cursor dead before partials written

  hipMemsetAsync(node_pool, 0, (size_t)N * D * 4, stream);
  hipMemsetAsync(degi, 0, (size_t)N * 4, stream);

  int eb = (E + 255) / 256;
  k_prep_w<<<8, 256, 0, stream>>>(W1, W2, wt);
  k_prep_x<<<(N * 32 + 255) / 256, 256, 0, stream>>>(x, t_hx, N * 32);
  k_count<<<eb, 256, 0, stream>>>(ei, E, degi);
  k_bsum<<<NB, 256, 0, stream>>>(degi, N, bsum);
  k_bscan<<<1, 256, 0, stream>>>(bsum, NB, boff, rowptr, N, E);
  k_rowptr<<<NB, 256, 0, stream>>>(degi, N, boff, rowptr, cursor);
  k_fill<<<eb, 256, 0, stream>>>(ei, E, cursor, col);
  k_bounds<<<1, 128, 0, stream>>>(batch, N, bound);

  int ab = (N + 3) / 4;
  for (int ll = 0; ll < LNUM; ++ll) {
    const unsigned short* hin = (ll == 0) ? t_hx : h;
    k_aggz<<<ab, 256, 0, stream>>>(hin, rowptr, col, N, z);
    k_gemm1<<<gb, 256, 0, stream>>>(z, wt + (size_t)ll * D * D, b1 + (size_t)ll * D,
                                    t_hx, partials, N);
    k_red1<<<64, 256, 0, stream>>>(partials, gb, partial2);
    k_finalize<<<1, 256, 0, stream>>>(partial2, gamma + (size_t)ll * D,
                                      beta + (size_t)ll * D, stats, N);
    k_gemm2<<<gb, 256, 0, stream>>>(t_hx, wt + (size_t)(LNUM + ll) * D * D,
                                    b2 + (size_t)ll * D, stats, h, node_pool, N);
  }
  k_gpool<<<GNUM, 256, 0, stream>>>(node_pool, bound, g_pool);
}

// Round 7
// 450.358 us; speedup vs baseline: 3.4094x; 1.0594x over previous
//
#include <hip/hip_runtime.h>

#define D 128
#define GNUM 64
#define LNUM 4
#define BN_EPS 1e-5f
#define EPB 16384          // edges per hist/scatter block
#define SH_MAX 12544       // max NBIN*B the one-block scan supports

typedef short bf16x8 __attribute__((ext_vector_type(8)));       // 8 bf16 = 4 VGPR
typedef float f32x4 __attribute__((ext_vector_type(4)));
typedef unsigned short u16x8 __attribute__((ext_vector_type(8)));
typedef unsigned short u16x4 __attribute__((ext_vector_type(4)));

__device__ __forceinline__ float bf2f(unsigned short u) {
  union { unsigned int i; float f; } v; v.i = ((unsigned int)u) << 16; return v.f;
}
__device__ __forceinline__ unsigned short f2bf(float f) {
  union { float f; unsigned int i; } v; v.f = f;
  unsigned int b = v.i;
  return (unsigned short)((b + 0x7FFFu + ((b >> 16) & 1u)) >> 16);
}

// ---------------- CSR build: atomic-free binned counting sort ----------------
// bin = dst >> 8  (256 nodes per bin)

// stage 1: per-block histogram -> hist[bin*B + block]
__global__ __launch_bounds__(256) void k_hist(const int* __restrict__ ei, int E,
                                              int B, int nbin, int* __restrict__ hist) {
  __shared__ int lh[256];
  int b = blockIdx.x, tx = threadIdx.x;
  lh[tx] = 0;
  __syncthreads();
  int s = b * EPB, e = min(s + EPB, E);
  for (int j = s + tx; j < e; j += 256) atomicAdd(&lh[ei[(size_t)E + j] >> 8], 1);
  __syncthreads();
  if (tx < nbin) hist[tx * B + b] = lh[tx];
}

// stage 2: one-block exclusive scan of hist (all in LDS) -> off; rowptr[N]=E
__global__ __launch_bounds__(1024) void k_hscan(const int* __restrict__ hist, int M,
                                                int* __restrict__ off,
                                                int* __restrict__ rowptr, int N, int E) {
  __shared__ int sh[SH_MAX];
  __shared__ int sh2[1024];
  int tx = threadIdx.x;
  int chunk = (M + 1023) / 1024;
  for (int i = 0; i < chunk; ++i) {
    int idx = tx * chunk + i;
    sh[idx] = (idx < M) ? hist[idx] : 0;
  }
  __syncthreads();
  int s = 0;
  for (int i = 0; i < chunk; ++i) s += sh[tx * chunk + i];
  sh2[tx] = s;
  __syncthreads();
  for (int o = 1; o < 1024; o <<= 1) {
    int u = (tx >= o) ? sh2[tx - o] : 0;
    __syncthreads();
    sh2[tx] += u;
    __syncthreads();
  }
  int run = (tx == 0) ? 0 : sh2[tx - 1];
  for (int i = 0; i < chunk; ++i) {
    int idx = tx * chunk + i;
    if (idx < M) { int v = sh[idx]; off[idx] = run; run += v; }
  }
  if (tx == 0) rowptr[N] = E;
}

// stage 3: scatter (dst,src) into per-(block,bin) contiguous runs
__global__ __launch_bounds__(256) void k_scatter(const int* __restrict__ ei, int E,
                                                 int B, int nbin,
                                                 const int* __restrict__ off,
                                                 int2* __restrict__ sorted) {
  __shared__ int cur[256];
  int b = blockIdx.x, tx = threadIdx.x;
  if (tx < nbin) cur[tx] = off[tx * B + b];
  __syncthreads();
  int s = b * EPB, e = min(s + EPB, E);
  for (int j = s + tx; j < e; j += 256) {
    int d = ei[(size_t)E + j];
    int sc = ei[j];
    int p = atomicAdd(&cur[d >> 8], 1);
    sorted[p] = make_int2(d, sc);
  }
}

// stage 4: one block per bin -> rowptr + col (bin's col span written by one block)
__global__ __launch_bounds__(256) void k_build(const int2* __restrict__ sorted,
                                               const int* __restrict__ off,
                                               int B, int nbin, int E, int N,
                                               int* __restrict__ rowptr,
                                               int* __restrict__ col) {
  __shared__ int cnt[256], excl[256], cur[256];
  int beta = blockIdx.x, tx = threadIdx.x;
  int s = off[beta * B];
  int e = (beta + 1 < nbin) ? off[(beta + 1) * B] : E;
  cnt[tx] = 0;
  __syncthreads();
  for (int j = s + tx; j < e; j += 256) atomicAdd(&cnt[sorted[j].x & 255], 1);
  __syncthreads();
  int v = cnt[tx];
  excl[tx] = v;
  __syncthreads();
  for (int o = 1; o < 256; o <<= 1) {
    int u = (tx >= o) ? excl[tx - o] : 0;
    __syncthreads();
    excl[tx] += u;
    __syncthreads();
  }
  int ex = excl[tx] - v;  // exclusive prefix within bin
  int n = beta * 256 + tx;
  if (n < N) rowptr[n] = s + ex;
  cur[tx] = s + ex;
  __syncthreads();
  for (int j = s + tx; j < e; j += 256) {
    int2 p = sorted[j];
    int q = atomicAdd(&cur[p.x & 255], 1);
    col[q] = p.y;
  }
}

// graph boundaries via binary search on sorted batch
__global__ void k_bounds(const int* __restrict__ batch, int N, int* __restrict__ bound) {
  int g = threadIdx.x;
  if (g > GNUM) return;
  int lo = 0, hi = N;
  while (lo < hi) { int mid = (lo + hi) >> 1; if (batch[mid] < g) lo = mid + 1; else hi = mid; }
  bound[g] = lo;
}

// ---------------- prep: fp32 -> bf16 ----------------
__global__ void k_prep_x(const float* __restrict__ x, unsigned short* __restrict__ hx, int total4) {
  int i = blockIdx.x * 256 + threadIdx.x;
  if (i < total4) {
    f32x4 v = ((const f32x4*)x)[i];
    u16x4 o; o[0] = f2bf(v[0]); o[1] = f2bf(v[1]); o[2] = f2bf(v[2]); o[3] = f2bf(v[3]);
    ((u16x4*)hx)[i] = o;
  }
}

// transpose W[k][n] -> wt[n][k], bf16.  blockIdx.x = matrix index (0..7)
__global__ __launch_bounds__(256) void k_prep_w(const float* __restrict__ W1,
                                                const float* __restrict__ W2,
                                                unsigned short* __restrict__ wt) {
  int l = blockIdx.x;
  const float* W = (l < LNUM) ? (W1 + (size_t)l * D * D) : (W2 + (size_t)(l - LNUM) * D * D);
  unsigned short* o = wt + (size_t)l * D * D;
#pragma unroll
  for (int i = 0; i < 64; ++i) {
    int idx = threadIdx.x + 256 * i;       // idx = k*128 + n
    int k = idx >> 7, n = idx & 127;
    o[n * D + k] = f2bf(W[idx]);
  }
}

// ---------------- aggregation: z = h + mean_nbr(h), bf16 ----------------
// One wave per node; 4 groups of 16 lanes each process a different edge,
// each lane loads 16B of the 256B row; unroll x2 -> up to 8 rows in flight.
__global__ __launch_bounds__(256) void k_aggz(const unsigned short* __restrict__ hin,
                                              const int* __restrict__ rowptr,
                                              const int* __restrict__ col,
                                              int N, unsigned short* __restrict__ z) {
  int tx = threadIdx.x;
  int w = tx >> 6, l = tx & 63;
  int g = l >> 4;             // edge subgroup 0..3
  int c = l & 15;             // 16B slice of the row
  int n = blockIdx.x * 4 + w;
  if (n >= N) return;
  int e0 = rowptr[n], e1 = rowptr[n + 1];
  const u16x8* h8 = (const u16x8*)hin;   // one row = 16 x u16x8
  f32x4 a0 = {0.f, 0.f, 0.f, 0.f}, a1 = {0.f, 0.f, 0.f, 0.f};
  f32x4 b0 = {0.f, 0.f, 0.f, 0.f}, b1 = {0.f, 0.f, 0.f, 0.f};
  int j = e0 + g;
  for (; j + 4 < e1; j += 8) {
    int cj0 = col[j];
    int cj1 = col[j + 4];
    u16x8 v0 = h8[(size_t)cj0 * 16 + c];
    u16x8 v1 = h8[(size_t)cj1 * 16 + c];
    a0[0] += bf2f(v0[0]); a0[1] += bf2f(v0[1]); a0[2] += bf2f(v0[2]); a0[3] += bf2f(v0[3]);
    a1[0] += bf2f(v0[4]); a1[1] += bf2f(v0[5]); a1[2] += bf2f(v0[6]); a1[3] += bf2f(v0[7]);
    b0[0] += bf2f(v1[0]); b0[1] += bf2f(v1[1]); b0[2] += bf2f(v1[2]); b0[3] += bf2f(v1[3]);
    b1[0] += bf2f(v1[4]); b1[1] += bf2f(v1[5]); b1[2] += bf2f(v1[6]); b1[3] += bf2f(v1[7]);
  }
  if (j < e1) {
    int cj = col[j];
    u16x8 v = h8[(size_t)cj * 16 + c];
    a0[0] += bf2f(v[0]); a0[1] += bf2f(v[1]); a0[2] += bf2f(v[2]); a0[3] += bf2f(v[3]);
    a1[0] += bf2f(v[4]); a1[1] += bf2f(v[5]); a1[2] += bf2f(v[6]); a1[3] += bf2f(v[7]);
  }
  a0 += b0; a1 += b1;
#pragma unroll
  for (int m = 16; m <= 32; m <<= 1) {
#pragma unroll
    for (int i = 0; i < 4; ++i) {
      a0[i] += __shfl_xor(a0[i], m, 64);
      a1[i] += __shfl_xor(a1[i], m, 64);
    }
  }
  if (g == 0) {
    float inv = (e1 > e0) ? 1.f / (float)(e1 - e0) : 0.f;
    u16x8 hv = h8[(size_t)n * 16 + c];
    u16x8 o;
    o[0] = f2bf(bf2f(hv[0]) + a0[0] * inv);
    o[1] = f2bf(bf2f(hv[1]) + a0[1] * inv);
    o[2] = f2bf(bf2f(hv[2]) + a0[2] * inv);
    o[3] = f2bf(bf2f(hv[3]) + a0[3] * inv);
    o[4] = f2bf(bf2f(hv[4]) + a1[0] * inv);
    o[5] = f2bf(bf2f(hv[5]) + a1[1] * inv);
    o[6] = f2bf(bf2f(hv[6]) + a1[2] * inv);
    o[7] = f2bf(bf2f(hv[7]) + a1[3] * inv);
    ((u16x8*)z)[(size_t)n * 16 + c] = o;
  }
}

// ---------------- GEMM1: t = z @ W1 + b1 (bf16 MFMA), + BN partials ----------------
__global__ __launch_bounds__(256) void k_gemm1(const unsigned short* __restrict__ z,
                                               const unsigned short* __restrict__ wt,
                                               const float* __restrict__ bias,
                                               unsigned short* __restrict__ t,
                                               float* __restrict__ partials, int N) {
  __shared__ union { unsigned short zt[64 * D]; float red[2 * 8 * D]; } uA;  // 16KB/8KB
  __shared__ union { unsigned short wl[D * D]; float out[64 * D]; } uB;      // 32KB
  int tx = threadIdx.x;
  int r0 = blockIdx.x * 64;
  const u16x8* zg = (const u16x8*)(z + (size_t)r0 * D);
#pragma unroll
  for (int i = 0; i < 4; ++i) {
    int cid = tx + 256 * i;
    int row = cid >> 4, c16 = cid & 15;
    u16x8 v = zg[cid];
    *(u16x8*)((char*)uA.zt + row * 256 + ((c16 * 16) ^ ((row & 7) << 4))) = v;
  }
  const u16x8* wg = (const u16x8*)wt;
#pragma unroll
  for (int i = 0; i < 8; ++i) {
    int cid = tx + 256 * i;
    int row = cid >> 4, c16 = cid & 15;
    u16x8 v = wg[cid];
    *(u16x8*)((char*)uB.wl + row * 256 + ((c16 * 16) ^ ((row & 7) << 4))) = v;
  }
  __syncthreads();
  int l = tx & 63, w = tx >> 6;
  int lm = l & 15, lg = l >> 4;
  f32x4 acc[8];
#pragma unroll
  for (int c = 0; c < 8; ++c) { float bv = bias[c * 16 + lm]; acc[c] = (f32x4){bv, bv, bv, bv}; }
  int arow = 16 * w + lm;
  const char* zb = (const char*)uA.zt + arow * 256;
  int aswz = (arow & 7) << 4;
#pragma unroll
  for (int kt = 0; kt < 4; ++kt) {
    int koff = kt * 64 + lg * 16;
    bf16x8 af = *(const bf16x8*)(zb + (koff ^ aswz));
#pragma unroll
    for (int c = 0; c < 8; ++c) {
      int n = c * 16 + lm;
      bf16x8 bfr = *(const bf16x8*)((const char*)uB.wl + n * 256 + (koff ^ ((n & 7) << 4)));
      acc[c] = __builtin_amdgcn_mfma_f32_16x16x32_bf16(af, bfr, acc[c], 0, 0, 0);
    }
  }
  __syncthreads();  // wl free -> out
#pragma unroll
  for (int c = 0; c < 8; ++c)
#pragma unroll
    for (int r = 0; r < 4; ++r)
      uB.out[(16 * w + 4 * lg + r) * D + c * 16 + lm] = acc[c][r];
  __syncthreads();
  int tc = tx & 31, tr = tx >> 5;
  f32x4 s = {0.f, 0.f, 0.f, 0.f}, q = {0.f, 0.f, 0.f, 0.f};
#pragma unroll
  for (int i = 0; i < 8; ++i) {
    int row = i * 8 + tr;
    f32x4 v = *(f32x4*)&uB.out[row * D + tc * 4];
    u16x4 o; o[0] = f2bf(v[0]); o[1] = f2bf(v[1]); o[2] = f2bf(v[2]); o[3] = f2bf(v[3]);
    *(u16x4*)(t + (size_t)(r0 + row) * D + tc * 4) = o;   // t is padded
    if (r0 + row < N) { s += v; q += v * v; }
  }
  *(f32x4*)&uA.red[tr * D + tc * 4] = s;
  *(f32x4*)&uA.red[8 * D + tr * D + tc * 4] = q;
  __syncthreads();
  int colx = tx & 127, which = tx >> 7;
  float S = 0.f;
#pragma unroll
  for (int j = 0; j < 8; ++j) S += uA.red[which * 8 * D + j * D + colx];
  partials[(size_t)blockIdx.x * 256 + tx] = S;
}

// reduce stage 1: 64 blocks stride over gemm1 blocks -> partial2[64][256]
__global__ __launch_bounds__(256) void k_red1(const float* __restrict__ partials, int NB,
                                              float* __restrict__ partial2) {
  int tx = threadIdx.x;
  float S = 0.f;
  for (int b = blockIdx.x; b < NB; b += 64) S += partials[(size_t)b * 256 + tx];
  partial2[(size_t)blockIdx.x * 256 + tx] = S;
}

// reduce stage 2 -> stats[0..127]=gamma*rstd, stats[128..255]=beta-mu*gamma*rstd
__global__ __launch_bounds__(256) void k_finalize(const float* __restrict__ partial2,
                                                  const float* __restrict__ gamma,
                                                  const float* __restrict__ beta,
                                                  float* __restrict__ stats, int N) {
  __shared__ float sh[256];
  int tx = threadIdx.x;
  float S = 0.f;
#pragma unroll 8
  for (int b = 0; b < 64; ++b) S += partial2[(size_t)b * 256 + tx];
  sh[tx] = S;
  __syncthreads();
  if (tx < D) {
    float mu = sh[tx] / (float)N;
    float var = sh[D + tx] / (float)N - mu * mu;
    float rstd = rsqrtf(fmaxf(var, 0.f) + BN_EPS);
    float A = gamma[tx] * rstd;
    stats[tx] = A;
    stats[D + tx] = beta[tx] - mu * A;
  }
}

// ---------------- GEMM2: h = relu(bn(t)) @ W2 + b2 ; node_pool += h ----------------
__global__ __launch_bounds__(256) void k_gemm2(const unsigned short* __restrict__ t,
                                               const unsigned short* __restrict__ wt,
                                               const float* __restrict__ bias,
                                               const float* __restrict__ stats,
                                               unsigned short* __restrict__ h,
                                               float* __restrict__ node_pool, int N) {
  __shared__ unsigned short at[64 * D];                                      // 16KB
  __shared__ union { unsigned short wl[D * D]; float out[64 * D]; } uB;      // 32KB
  int tx = threadIdx.x;
  int r0 = blockIdx.x * 64;
  const u16x8* tg = (const u16x8*)(t + (size_t)r0 * D);
#pragma unroll
  for (int i = 0; i < 4; ++i) {
    int cid = tx + 256 * i;
    int row = cid >> 4, c16 = cid & 15;
    u16x8 v = tg[cid];
    int c0 = c16 * 8;
    f32x4 a0 = *(const f32x4*)&stats[c0];
    f32x4 a1 = *(const f32x4*)&stats[c0 + 4];
    f32x4 b0 = *(const f32x4*)&stats[D + c0];
    f32x4 b1v = *(const f32x4*)&stats[D + c0 + 4];
    u16x8 o;
    o[0] = f2bf(fmaxf(bf2f(v[0]) * a0[0] + b0[0], 0.f));
    o[1] = f2bf(fmaxf(bf2f(v[1]) * a0[1] + b0[1], 0.f));
    o[2] = f2bf(fmaxf(bf2f(v[2]) * a0[2] + b0[2], 0.f));
    o[3] = f2bf(fmaxf(bf2f(v[3]) * a0[3] + b0[3], 0.f));
    o[4] = f2bf(fmaxf(bf2f(v[4]) * a1[0] + b1v[0], 0.f));
    o[5] = f2bf(fmaxf(bf2f(v[5]) * a1[1] + b1v[1], 0.f));
    o[6] = f2bf(fmaxf(bf2f(v[6]) * a1[2] + b1v[2], 0.f));
    o[7] = f2bf(fmaxf(bf2f(v[7]) * a1[3] + b1v[3], 0.f));
    *(u16x8*)((char*)at + row * 256 + ((c16 * 16) ^ ((row & 7) << 4))) = o;
  }
  const u16x8* wg = (const u16x8*)wt;
#pragma unroll
  for (int i = 0; i < 8; ++i) {
    int cid = tx + 256 * i;
    int row = cid >> 4, c16 = cid & 15;
    u16x8 v = wg[cid];
    *(u16x8*)((char*)uB.wl + row * 256 + ((c16 * 16) ^ ((row & 7) << 4))) = v;
  }
  __syncthreads();
  int l = tx & 63, w = tx >> 6;
  int lm = l & 15, lg = l >> 4;
  f32x4 acc[8];
#pragma unroll
  for (int c = 0; c < 8; ++c) { float bv = bias[c * 16 + lm]; acc[c] = (f32x4){bv, bv, bv, bv}; }
  int arow = 16 * w + lm;
  const char* ab = (const char*)at + arow * 256;
  int aswz = (arow & 7) << 4;
#pragma unroll
  for (int kt = 0; kt < 4; ++kt) {
    int koff = kt * 64 + lg * 16;
    bf16x8 af = *(const bf16x8*)(ab + (koff ^ aswz));
#pragma unroll
    for (int c = 0; c < 8; ++c) {
      int n = c * 16 + lm;
      bf16x8 bfr = *(const bf16x8*)((const char*)uB.wl + n * 256 + (koff ^ ((n & 7) << 4)));
      acc[c] = __builtin_amdgcn_mfma_f32_16x16x32_bf16(af, bfr, acc[c], 0, 0, 0);
    }
  }
  __syncthreads();
#pragma unroll
  for (int c = 0; c < 8; ++c)
#pragma unroll
    for (int r = 0; r < 4; ++r)
      uB.out[(16 * w + 4 * lg + r) * D + c * 16 + lm] = acc[c][r];
  __syncthreads();
  int tc = tx & 31, tr = tx >> 5;
#pragma unroll
  for (int i = 0; i < 8; ++i) {
    int row = i * 8 + tr;
    int gr = r0 + row;
    if (gr < N) {
      f32x4 v = *(f32x4*)&uB.out[row * D + tc * 4];
      f32x4* np = (f32x4*)(node_pool + (size_t)gr * D + tc * 4);
      f32x4 o = *np;
      o += v;
      *np = o;
      u16x4 hb; hb[0] = f2bf(v[0]); hb[1] = f2bf(v[1]); hb[2] = f2bf(v[2]); hb[3] = f2bf(v[3]);
      *(u16x4*)(h + (size_t)gr * D + tc * 4) = hb;
    }
  }
}

// ---------------- pooling: g_pool[g] = mean over rows of node_pool ----------------
__global__ __launch_bounds__(256) void k_gpool(const float* __restrict__ np,
                                               const int* __restrict__ bound,
                                               float* __restrict__ gp) {
  __shared__ float red[8 * D];
  int g = blockIdx.x;
  int s = bound[g], e = bound[g + 1];
  int tc = threadIdx.x & 31, tr = threadIdx.x >> 5;
  f32x4 a = {0.f, 0.f, 0.f, 0.f};
  for (int r = s + tr; r < e; r += 8)
    a += *(const f32x4*)(np + (size_t)r * D + tc * 4);
  *(f32x4*)&red[tr * D + tc * 4] = a;
  __syncthreads();
  if (threadIdx.x < D) {
    float v = 0.f;
#pragma unroll
    for (int j = 0; j < 8; ++j) v += red[j * D + threadIdx.x];
    float c = (float)(e - s);
    gp[(size_t)g * D + threadIdx.x] = v / fmaxf(c, 1.f);
  }
}

// ---------------- launch ----------------
extern "C" void kernel_launch(void* const* d_in, const int* in_sizes, int n_in,
                              void* d_out, int out_size, void* d_ws,
                              size_t ws_size, hipStream_t stream) {
  const float* x = (const float*)d_in[0];
  const int* ei = (const int*)d_in[1];
  const int* batch = (const int*)d_in[2];
  const float* W1 = (const float*)d_in[3];
  const float* b1 = (const float*)d_in[4];
  const float* gamma = (const float*)d_in[5];
  const float* beta = (const float*)d_in[6];
  const float* W2 = (const float*)d_in[7];
  const float* b2 = (const float*)d_in[8];
  int N = in_sizes[0] / D;
  int E = in_sizes[1] / 2;
  int Npad = (N + 63) & ~63;
  int gb = Npad / 64;
  int B = (E + EPB - 1) / EPB;       // hist/scatter blocks (49 for E=800k)
  int nbin = (N + 255) / 256;        // 196 for N=50k
  int M = nbin * B;                  // 9604 <= SH_MAX

  float* out = (float*)d_out;
  float* node_pool = out;
  float* g_pool = out + (size_t)N * D;

  char* wp = (char*)d_ws;
  unsigned short* t_hx = (unsigned short*)wp; wp += (size_t)Npad * D * 2;  // t, aliased x-bf16
  unsigned short* h = (unsigned short*)wp;    wp += (size_t)Npad * D * 2;
  unsigned short* z = (unsigned short*)wp;    wp += (size_t)Npad * D * 2;
  unsigned short* wt = (unsigned short*)wp;   wp += (size_t)8 * D * D * 2;
  float* partials = (float*)wp;               wp += (size_t)gb * 256 * 4;
  float* partial2 = (float*)wp;               wp += (size_t)64 * 256 * 4;
  float* stats = (float*)wp;                  wp += (size_t)2 * D * 4;
  int* bound = (int*)wp;                      wp += (size_t)(GNUM + 4) * 4;
  int* rowptr = (int*)wp;                     wp += (size_t)(N + 1) * 4;
  int* hist = (int*)wp;                       wp += (size_t)SH_MAX * 4;
  int* off = (int*)wp;                        wp += (size_t)SH_MAX * 4;
  int* col = (int*)wp;                        wp += (size_t)E * 4;
  int2* sorted = (int2*)wp;                   wp += (size_t)E * 8;   // own buffer (no alias)

  hipMemsetAsync(node_pool, 0, (size_t)N * D * 4, stream);
  if (Npad > N) {  // pad hygiene: no kernel ever reads poisoned/stale bytes
    size_t padB = (size_t)(Npad - N) * D * 2;
    hipMemsetAsync(t_hx + (size_t)N * D, 0, padB, stream);
    hipMemsetAsync(h + (size_t)N * D, 0, padB, stream);
    hipMemsetAsync(z + (size_t)N * D, 0, padB, stream);
  }

  k_prep_w<<<8, 256, 0, stream>>>(W1, W2, wt);
  k_prep_x<<<(N * 32 + 255) / 256, 256, 0, stream>>>(x, t_hx, N * 32);
  k_hist<<<B, 256, 0, stream>>>(ei, E, B, nbin, hist);
  k_hscan<<<1, 1024, 0, stream>>>(hist, M, off, rowptr, N, E);
  k_scatter<<<B, 256, 0, stream>>>(ei, E, B, nbin, off, sorted);
  k_build<<<nbin, 256, 0, stream>>>(sorted, off, B, nbin, E, N, rowptr, col);
  k_bounds<<<1, 128, 0, stream>>>(batch, N, bound);

  int ab = (N + 3) / 4;
  for (int ll = 0; ll < LNUM; ++ll) {
    const unsigned short* hin = (ll == 0) ? t_hx : h;
    k_aggz<<<ab, 256, 0, stream>>>(hin, rowptr, col, N, z);
    k_gemm1<<<gb, 256, 0, stream>>>(z, wt + (size_t)ll * D * D, b1 + (size_t)ll * D,
                                    t_hx, partials, N);
    k_red1<<<64, 256, 0, stream>>>(partials, gb, partial2);
    k_finalize<<<1, 256, 0, stream>>>(partial2, gamma + (size_t)ll * D,
                                      beta + (size_t)ll * D, stats, N);
    k_gemm2<<<gb, 256, 0, stream>>>(t_hx, wt + (size_t)(LNUM + ll) * D * D,
                                    b2 + (size_t)ll * D, stats, h, node_pool, N);
  }
  k_gpool<<<GNUM, 256, 0, stream>>>(node_pool, bound, g_pool);
}